// Round 1
// baseline (15353.261 us; speedup 1.0000x reference)
//
#include <hip/hip_runtime.h>
#include <cmath>

#define WGS 256
#define NWG 64

// ---------------- sizes ----------------
#define B_   32
#define S_   200
#define L_   50
#define H_   512
#define DE_  256
#define VS_  30000
#define TD_  49          // L-1 decoder steps
#define G3_  1536        // 3*H

// ws layout (float offsets)
#define OFF_ENC_GX  ((size_t)0)                         // [200][32][1536]
#define SZ_ENC_GX   ((size_t)S_*B_*G3_)                 // 9830400
#define OFF_DEC_GX  (OFF_ENC_GX + SZ_ENC_GX)            // [49][32][1536]
#define SZ_DEC_GX   ((size_t)TD_*B_*G3_)                // 2408448
#define OFF_ENC_OUT (OFF_DEC_GX + SZ_DEC_GX)            // [32][200][512]
#define SZ_ENC_OUT  ((size_t)B_*S_*H_)                  // 3276800
#define OFF_HBUF    (OFF_ENC_OUT + SZ_ENC_OUT)          // [2][32][512]
#define SZ_HBUF     ((size_t)2*B_*H_)                   // 32768
#define OFF_SCORES  (OFF_HBUF + SZ_HBUF)                // [32][200]
#define SZ_SCORES   ((size_t)B_*S_)                     // 6400
#define OFF_CMAT    (OFF_SCORES + SZ_SCORES)            // [49][32][1024]
#define SZ_CMAT     ((size_t)TD_*B_*2*H_)               // 1605632
#define OFF_OUT1    (OFF_CMAT + SZ_CMAT)                // [1568][512]
#define SZ_OUT1     ((size_t)TD_*B_*H_)                 // 802816
#define OFF_BAR     (OFF_OUT1 + SZ_OUT1)                // 1 unsigned

// ---------------- grid barrier (monotonic counter, 64 resident WGs) ----------------
__device__ __forceinline__ void gbar(unsigned* bar, unsigned target) {
  __syncthreads();
  if (threadIdx.x == 0) {
    __threadfence();
    __hip_atomic_fetch_add(bar, 1u, __ATOMIC_RELEASE, __HIP_MEMORY_SCOPE_AGENT);
    while (__hip_atomic_load(bar, __ATOMIC_ACQUIRE, __HIP_MEMORY_SCOPE_AGENT) < target) {
      __builtin_amdgcn_s_sleep(1);
    }
    __threadfence();
  }
  __syncthreads();
}

// ---------------- persistent recurrence kernel ----------------
// 64 WGs x 256 threads. Encoder: thread=(b=t>>3, jl=t&7), WG owns j in [w*8, w*8+8).
__global__ __launch_bounds__(WGS)
void recurrence_kernel(const float* __restrict__ enc_gx,
                       const float* __restrict__ dec_gx,
                       const float* __restrict__ eWhh, const float* __restrict__ eBhh,
                       const float* __restrict__ dWhh, const float* __restrict__ dBhh,
                       float* __restrict__ enc_out,
                       float* __restrict__ hbuf,
                       float* __restrict__ scores,
                       float* __restrict__ Cmat,
                       unsigned* __restrict__ bar)
{
  const int t  = threadIdx.x;
  const int w  = blockIdx.x;
  const int b  = t >> 3;
  const int jl = t & 7;
  const int j  = (w << 3) + jl;
  unsigned bt = 0;
  int cur = 0;

  // -------- encoder: 200 steps --------
  {
    const float* wr = eWhh + (size_t)j * H_;
    const float* wz = eWhh + (size_t)(H_ + j) * H_;
    const float* wn = eWhh + (size_t)(2 * H_ + j) * H_;
    const float br_ = eBhh[j], bz_ = eBhh[H_ + j], bn_ = eBhh[2 * H_ + j];
    for (int s = 0; s < S_; ++s) {
      const float* h = hbuf + cur * (B_ * H_) + (b << 9);
      float ar = 0.f, az = 0.f, an = 0.f;
      #pragma unroll 4
      for (int k = 0; k < H_; k += 4) {
        float4 hv = *(const float4*)(h + k);
        float4 rv = *(const float4*)(wr + k);
        float4 zv = *(const float4*)(wz + k);
        float4 nv = *(const float4*)(wn + k);
        ar += hv.x * rv.x + hv.y * rv.y + hv.z * rv.z + hv.w * rv.w;
        az += hv.x * zv.x + hv.y * zv.y + hv.z * zv.z + hv.w * zv.w;
        an += hv.x * nv.x + hv.y * nv.y + hv.z * nv.z + hv.w * nv.w;
      }
      const float* gx = enc_gx + ((size_t)s * B_ + b) * G3_;
      float r = 1.f / (1.f + expf(-(gx[j] + ar + br_)));
      float z = 1.f / (1.f + expf(-(gx[H_ + j] + az + bz_)));
      float n = tanhf(gx[2 * H_ + j] + r * (an + bn_));
      float hn = (1.f - z) * n + z * h[j];
      hbuf[(cur ^ 1) * (B_ * H_) + (b << 9) + j] = hn;
      enc_out[((size_t)b * S_ + s) * H_ + j] = hn;
      cur ^= 1;
      bt += NWG; gbar(bar, bt);
    }
  }

  // -------- decoder: 49 steps --------
  const float* dwr = dWhh + (size_t)j * H_;
  const float* dwz = dWhh + (size_t)(H_ + j) * H_;
  const float* dwn = dWhh + (size_t)(2 * H_ + j) * H_;
  const float dbr = dBhh[j], dbz = dBhh[H_ + j], dbn = dBhh[2 * H_ + j];
  const int bb = w & 31, half = w >> 5;

  for (int td = 0; td < TD_; ++td) {
    // --- phase A: GRU step ---
    {
      const float* h = hbuf + cur * (B_ * H_) + (b << 9);
      float ar = 0.f, az = 0.f, an = 0.f;
      #pragma unroll 4
      for (int k = 0; k < H_; k += 4) {
        float4 hv = *(const float4*)(h + k);
        float4 rv = *(const float4*)(dwr + k);
        float4 zv = *(const float4*)(dwz + k);
        float4 nv = *(const float4*)(dwn + k);
        ar += hv.x * rv.x + hv.y * rv.y + hv.z * rv.z + hv.w * rv.w;
        az += hv.x * zv.x + hv.y * zv.y + hv.z * zv.z + hv.w * zv.w;
        an += hv.x * nv.x + hv.y * nv.y + hv.z * nv.z + hv.w * nv.w;
      }
      const float* gx = dec_gx + ((size_t)td * B_ + b) * G3_;
      float r = 1.f / (1.f + expf(-(gx[j] + ar + dbr)));
      float z = 1.f / (1.f + expf(-(gx[H_ + j] + az + dbz)));
      float n = tanhf(gx[2 * H_ + j] + r * (an + dbn));
      float hn = (1.f - z) * n + z * h[j];
      hbuf[(cur ^ 1) * (B_ * H_) + (b << 9) + j] = hn;
      Cmat[((size_t)td * B_ + b) * (2 * H_) + H_ + j] = hn;   // concat second half = h
      cur ^= 1;
    }
    bt += NWG; gbar(bar, bt);

    // --- phase B: attention scores (WG = (bb, half of i-range)) ---
    {
      const float* h = hbuf + cur * (B_ * H_) + (bb << 9);
      int il = t >> 1, kg = t & 1;
      float part = 0.f;
      if (il < 100) {
        int i = half * 100 + il;
        const float* eo = enc_out + ((size_t)bb * S_ + i) * H_ + (kg << 8);
        const float* hh = h + (kg << 8);
        #pragma unroll 4
        for (int k = 0; k < 256; k += 4) {
          float4 e4 = *(const float4*)(eo + k);
          float4 h4 = *(const float4*)(hh + k);
          part += e4.x * h4.x + e4.y * h4.y + e4.z * h4.z + e4.w * h4.w;
        }
      }
      __shared__ float sred[WGS];
      sred[t] = part;
      __syncthreads();
      if (kg == 0 && il < 100) scores[bb * S_ + half * 100 + il] = sred[t] + sred[t + 1];
      __syncthreads();
    }
    bt += NWG; gbar(bar, bt);

    // --- phase C: softmax + ctx partial (atomicAdd; 2 commutative adds -> deterministic) ---
    {
      __shared__ float red[WGS];
      float sv = (t < S_) ? scores[bb * S_ + t] : -1e30f;
      red[t] = sv; __syncthreads();
      for (int off = 128; off; off >>= 1) { if (t < off) red[t] = fmaxf(red[t], red[t + off]); __syncthreads(); }
      float mx = red[0]; __syncthreads();
      float ev = (t < S_) ? expf(sv - mx) : 0.f;
      red[t] = ev; __syncthreads();
      for (int off = 128; off; off >>= 1) { if (t < off) red[t] += red[t + off]; __syncthreads(); }
      float inv = 1.f / red[0];
      __shared__ float p[100];
      if (t >= half * 100 && t < half * 100 + 100) p[t - half * 100] = ev * inv;
      __syncthreads();
      const float* eo = enc_out + ((size_t)bb * S_ + half * 100) * H_ + (t << 1);
      float ax = 0.f, ay = 0.f;
      for (int i = 0; i < 100; ++i) {
        float pi = p[i];
        float2 v = *(const float2*)(eo + (size_t)i * H_);
        ax += pi * v.x; ay += pi * v.y;
      }
      float* cd = Cmat + ((size_t)td * B_ + bb) * (2 * H_) + (t << 1);
      atomicAdd(cd, ax);
      atomicAdd(cd + 1, ay);
      __syncthreads();
    }
    // no barrier needed here: next phase-A barrier separates C(td) from B(td+1)
  }
}

// ---------------- tiled fp32 GEMM: C[m][n] = act(sum_k A[m][k]*Bw[n][k] + bias[n]) ----------------
// MODE 0: A=enc_emb gathered via method_code, out enc_gx
// MODE 1: A=dec_emb gathered via method_summary, out dec_gx
// MODE 2: A=Cmat, relu, out OUT1
// MODE 3: A=OUT1, out d_out[b][td][n]
template<int MODE>
__launch_bounds__(WGS)
__global__ void gemm_bt(const float* __restrict__ A,
                        const int* __restrict__ idx,
                        const float* __restrict__ Bw,
                        const float* __restrict__ bias,
                        float* __restrict__ Cdst,
                        int M, int N, int K)
{
  const int BM = 64, BN = 64, BK = 16;
  __shared__ float As[BK][BM];
  __shared__ float Bs[BK][BN];
  __shared__ int toks[BM];
  const int m0 = blockIdx.y * BM, n0 = blockIdx.x * BN;
  const int t = threadIdx.x;
  const int tx = t & 15, ty = t >> 4;
  float acc[4][4] = {{0.f}};

  if (MODE <= 1) {
    if (t < BM) {
      int m = m0 + t;
      int tok = 0;
      if (m < M) {
        int bidx = m & 31, srow = m >> 5;
        tok = (MODE == 0) ? idx[bidx * S_ + srow] : idx[bidx * L_ + srow];
      }
      toks[t] = tok;
    }
    __syncthreads();
  }

  const int row = t >> 2, kk = (t & 3) * 4;
  for (int k0 = 0; k0 < K; k0 += BK) {
    {
      int m = m0 + row;
      float4 v = {0.f, 0.f, 0.f, 0.f};
      if (m < M) {
        const float* src = (MODE <= 1) ? (A + (size_t)toks[row] * K + k0 + kk)
                                       : (A + (size_t)m * K + k0 + kk);
        v = *(const float4*)src;
      }
      As[kk][row] = v.x; As[kk + 1][row] = v.y; As[kk + 2][row] = v.z; As[kk + 3][row] = v.w;
      int n = n0 + row;
      float4 wv = {0.f, 0.f, 0.f, 0.f};
      if (n < N) wv = *(const float4*)(Bw + (size_t)n * K + k0 + kk);
      Bs[kk][row] = wv.x; Bs[kk + 1][row] = wv.y; Bs[kk + 2][row] = wv.z; Bs[kk + 3][row] = wv.w;
    }
    __syncthreads();
    #pragma unroll
    for (int k = 0; k < BK; ++k) {
      float a[4], bq[4];
      *(float4*)a  = *(const float4*)&As[k][ty * 4];
      *(float4*)bq = *(const float4*)&Bs[k][tx * 4];
      #pragma unroll
      for (int i = 0; i < 4; ++i)
        #pragma unroll
        for (int jj = 0; jj < 4; ++jj)
          acc[i][jj] += a[i] * bq[jj];
    }
    __syncthreads();
  }

  #pragma unroll
  for (int i = 0; i < 4; ++i) {
    int m = m0 + ty * 4 + i;
    if (m >= M) continue;
    #pragma unroll
    for (int jj = 0; jj < 4; ++jj) {
      int n = n0 + tx * 4 + jj;
      if (n >= N) continue;
      float v = acc[i][jj] + bias[n];
      if (MODE == 2) v = fmaxf(v, 0.f);
      if (MODE == 3) {
        int bidx = m & 31, td = m >> 5;
        Cdst[((size_t)bidx * TD_ + td) * (size_t)VS_ + n] = v;
      } else {
        Cdst[(size_t)m * N + n] = v;
      }
    }
  }
}

// ---------------- launch ----------------
extern "C" void kernel_launch(void* const* d_in, const int* in_sizes, int n_in,
                              void* d_out, int out_size, void* d_ws, size_t ws_size,
                              hipStream_t stream) {
  const int*   method_code    = (const int*)d_in[0];
  const int*   method_summary = (const int*)d_in[1];
  // d_in[2] = use_teacher (always 1; reference teacher-forces unconditionally)
  const float* enc_emb = (const float*)d_in[3];
  const float* enc_Wih = (const float*)d_in[4];
  const float* enc_Whh = (const float*)d_in[5];
  const float* enc_bih = (const float*)d_in[6];
  const float* enc_bhh = (const float*)d_in[7];
  const float* dec_emb = (const float*)d_in[8];
  const float* dec_Wih = (const float*)d_in[9];
  const float* dec_Whh = (const float*)d_in[10];
  const float* dec_bih = (const float*)d_in[11];
  const float* dec_bhh = (const float*)d_in[12];
  const float* W1 = (const float*)d_in[13];
  const float* b1 = (const float*)d_in[14];
  const float* W2 = (const float*)d_in[15];
  const float* b2 = (const float*)d_in[16];

  float* ws      = (float*)d_ws;
  float* enc_gx  = ws + OFF_ENC_GX;
  float* dec_gx  = ws + OFF_DEC_GX;
  float* enc_out = ws + OFF_ENC_OUT;
  float* hbuf    = ws + OFF_HBUF;
  float* scores  = ws + OFF_SCORES;
  float* Cmat    = ws + OFF_CMAT;
  float* OUT1    = ws + OFF_OUT1;
  unsigned* bar  = (unsigned*)(ws + OFF_BAR);

  // zero state (ws is poisoned 0xAA before timing)
  hipMemsetAsync(bar, 0, sizeof(unsigned), stream);
  hipMemsetAsync(hbuf, 0, SZ_HBUF * sizeof(float), stream);
  hipMemsetAsync(Cmat, 0, SZ_CMAT * sizeof(float), stream);

  dim3 blk(WGS);
  // gx precompute (gather-GEMMs)
  gemm_bt<0><<<dim3(G3_ / 64, (S_ * B_) / 64), blk, 0, stream>>>(
      enc_emb, method_code, enc_Wih, enc_bih, enc_gx, S_ * B_, G3_, DE_);
  gemm_bt<1><<<dim3(G3_ / 64, (TD_ * B_ + 63) / 64), blk, 0, stream>>>(
      dec_emb, method_summary, dec_Wih, dec_bih, dec_gx, TD_ * B_, G3_, DE_);

  // persistent recurrence (encoder + attentive decoder)
  recurrence_kernel<<<NWG, blk, 0, stream>>>(enc_gx, dec_gx,
                                             enc_Whh, enc_bhh, dec_Whh, dec_bhh,
                                             enc_out, hbuf, scores, Cmat, bar);

  // output projection, batched over all 49*32 steps
  gemm_bt<2><<<dim3(H_ / 64, (TD_ * B_ + 63) / 64), blk, 0, stream>>>(
      Cmat, nullptr, W1, b1, OUT1, TD_ * B_, H_, 2 * H_);
  gemm_bt<3><<<dim3((VS_ + 63) / 64, (TD_ * B_ + 63) / 64), blk, 0, stream>>>(
      OUT1, nullptr, W2, b2, (float*)d_out, TD_ * B_, VS_, H_);
}

// Round 2
// 14293.599 us; speedup vs baseline: 1.0741x; 1.0741x over previous
//
#include <hip/hip_runtime.h>
#include <cmath>

#define WGS 256
#define NWG 64

// ---------------- sizes ----------------
#define B_   32
#define S_   200
#define L_   50
#define H_   512
#define DE_  256
#define VS_  30000
#define TD_  49          // L-1 decoder steps
#define G3_  1536        // 3*H

// ws layout (float offsets)
#define OFF_ENC_GX  ((size_t)0)                         // [200][32][1536]
#define SZ_ENC_GX   ((size_t)S_*B_*G3_)
#define OFF_DEC_GX  (OFF_ENC_GX + SZ_ENC_GX)            // [49][32][1536]
#define SZ_DEC_GX   ((size_t)TD_*B_*G3_)
#define OFF_ENC_OUT (OFF_DEC_GX + SZ_DEC_GX)            // [32][200][512]
#define SZ_ENC_OUT  ((size_t)B_*S_*H_)
#define OFF_HBUF    (OFF_ENC_OUT + SZ_ENC_OUT)          // [2][32][512]
#define SZ_HBUF     ((size_t)2*B_*H_)
#define OFF_CMAT    (OFF_HBUF + SZ_HBUF)                // [49][32][1024]
#define SZ_CMAT     ((size_t)TD_*B_*2*H_)
#define OFF_OUT1    (OFF_CMAT + SZ_CMAT)                // [1568][512]
#define SZ_OUT1     ((size_t)TD_*B_*H_)
#define OFF_BAR     (OFF_OUT1 + SZ_OUT1)                // flags[64*16] + go
#define SZ_BAR      ((size_t)(NWG*16 + 16))             // uints

// ---------------- two-phase grid barrier: no contended RMW ----------------
// Each WG posts its arrival (monotonic step) to its own cacheline; WG0's
// lanes t<NWG each spin one distinct flag; WG0 then release-stores `go`;
// all other WGs spin-read `go` (read-shared line, no RMW bouncing).
__device__ __forceinline__ void gbar(unsigned* __restrict__ flags,
                                     unsigned* __restrict__ go,
                                     unsigned step, int w, int t) {
  __syncthreads();
  if (w == 0) {
    if (t > 0 && t < NWG) {
      while (__hip_atomic_load(&flags[t * 16], __ATOMIC_ACQUIRE,
                               __HIP_MEMORY_SCOPE_AGENT) < step) { }
    }
    __syncthreads();
    if (t == 0) {
      __threadfence();
      __hip_atomic_store(go, step, __ATOMIC_RELEASE, __HIP_MEMORY_SCOPE_AGENT);
    }
    __syncthreads();
  } else {
    if (t == 0) {
      __threadfence();
      __hip_atomic_store(&flags[w * 16], step, __ATOMIC_RELEASE,
                         __HIP_MEMORY_SCOPE_AGENT);
      while (__hip_atomic_load(go, __ATOMIC_ACQUIRE,
                               __HIP_MEMORY_SCOPE_AGENT) < step) { }
    }
    __syncthreads();
  }
}

// ---------------- persistent GRU-chain kernel (encoder + decoder h-chain) ----------------
// 64 WGs x 256 threads. thread=(b=t>>3, jl=t&7); WG owns j in [w*8, w*8+8).
__global__ __launch_bounds__(WGS)
void recurrence_kernel(const float* __restrict__ enc_gx,
                       const float* __restrict__ dec_gx,
                       const float* __restrict__ eWhh, const float* __restrict__ eBhh,
                       const float* __restrict__ dWhh, const float* __restrict__ dBhh,
                       float* __restrict__ enc_out,
                       float* __restrict__ hbuf,
                       float* __restrict__ Cmat,
                       unsigned* __restrict__ barmem)
{
  const int t  = threadIdx.x;
  const int w  = blockIdx.x;
  const int b  = t >> 3;
  const int jl = t & 7;
  const int j  = (w << 3) + jl;
  unsigned* flags = barmem;
  unsigned* go    = barmem + NWG * 16;
  unsigned step = 0;
  int cur = 0;

  // -------- encoder: 200 steps --------
  {
    const float* wr = eWhh + (size_t)j * H_;
    const float* wz = eWhh + (size_t)(H_ + j) * H_;
    const float* wn = eWhh + (size_t)(2 * H_ + j) * H_;
    const float br_ = eBhh[j], bz_ = eBhh[H_ + j], bn_ = eBhh[2 * H_ + j];
    for (int s = 0; s < S_; ++s) {
      const float* h = hbuf + cur * (B_ * H_) + (b << 9);
      float ar = 0.f, az = 0.f, an = 0.f;
      #pragma unroll 4
      for (int k = 0; k < H_; k += 4) {
        float4 hv = *(const float4*)(h + k);
        float4 rv = *(const float4*)(wr + k);
        float4 zv = *(const float4*)(wz + k);
        float4 nv = *(const float4*)(wn + k);
        ar += hv.x * rv.x + hv.y * rv.y + hv.z * rv.z + hv.w * rv.w;
        az += hv.x * zv.x + hv.y * zv.y + hv.z * zv.z + hv.w * zv.w;
        an += hv.x * nv.x + hv.y * nv.y + hv.z * nv.z + hv.w * nv.w;
      }
      const float* gx = enc_gx + ((size_t)s * B_ + b) * G3_;
      float r = 1.f / (1.f + expf(-(gx[j] + ar + br_)));
      float z = 1.f / (1.f + expf(-(gx[H_ + j] + az + bz_)));
      float n = tanhf(gx[2 * H_ + j] + r * (an + bn_));
      float hn = (1.f - z) * n + z * h[j];
      hbuf[(cur ^ 1) * (B_ * H_) + (b << 9) + j] = hn;
      enc_out[((size_t)b * S_ + s) * H_ + j] = hn;
      cur ^= 1;
      ++step; gbar(flags, go, step, w, t);
    }
  }

  // -------- decoder h-chain: 49 steps (attention is a separate kernel) --------
  {
    const float* wr = dWhh + (size_t)j * H_;
    const float* wz = dWhh + (size_t)(H_ + j) * H_;
    const float* wn = dWhh + (size_t)(2 * H_ + j) * H_;
    const float br_ = dBhh[j], bz_ = dBhh[H_ + j], bn_ = dBhh[2 * H_ + j];
    for (int td = 0; td < TD_; ++td) {
      const float* h = hbuf + cur * (B_ * H_) + (b << 9);
      float ar = 0.f, az = 0.f, an = 0.f;
      #pragma unroll 4
      for (int k = 0; k < H_; k += 4) {
        float4 hv = *(const float4*)(h + k);
        float4 rv = *(const float4*)(wr + k);
        float4 zv = *(const float4*)(wz + k);
        float4 nv = *(const float4*)(wn + k);
        ar += hv.x * rv.x + hv.y * rv.y + hv.z * rv.z + hv.w * rv.w;
        az += hv.x * zv.x + hv.y * zv.y + hv.z * zv.z + hv.w * zv.w;
        an += hv.x * nv.x + hv.y * nv.y + hv.z * nv.z + hv.w * nv.w;
      }
      const float* gx = dec_gx + ((size_t)td * B_ + b) * G3_;
      float r = 1.f / (1.f + expf(-(gx[j] + ar + br_)));
      float z = 1.f / (1.f + expf(-(gx[H_ + j] + az + bz_)));
      float n = tanhf(gx[2 * H_ + j] + r * (an + bn_));
      float hn = (1.f - z) * n + z * h[j];
      hbuf[(cur ^ 1) * (B_ * H_) + (b << 9) + j] = hn;
      Cmat[((size_t)td * B_ + b) * (2 * H_) + H_ + j] = hn;   // concat second half = h
      cur ^= 1;
      if (td < TD_ - 1) { ++step; gbar(flags, go, step, w, t); }
      // last step: kernel end is the sync
    }
  }
}

// ---------------- attention kernel: one WG per (td, b) ----------------
// scores = enc_out[b] @ h ; softmax ; ctx = p @ enc_out[b] -> Cmat first half
__global__ __launch_bounds__(WGS)
void attention_kernel(const float* __restrict__ enc_out,
                      float* __restrict__ Cmat)
{
  const int task = blockIdx.x;          // td*32 + b
  const int td = task >> 5, b = task & 31;
  const int t = threadIdx.x;
  const float* h = Cmat + ((size_t)td * B_ + b) * (2 * H_) + H_;

  __shared__ float red[WGS];
  __shared__ float p[WGS];              // 200 used

  float sv = -1e30f;
  if (t < S_) {
    const float* eo = enc_out + ((size_t)b * S_ + t) * H_;
    float acc = 0.f;
    #pragma unroll 4
    for (int k = 0; k < H_; k += 4) {
      float4 e = *(const float4*)(eo + k);
      float4 hv = *(const float4*)(h + k);
      acc += e.x * hv.x + e.y * hv.y + e.z * hv.z + e.w * hv.w;
    }
    sv = acc;
  }
  red[t] = sv; __syncthreads();
  for (int o = 128; o; o >>= 1) { if (t < o) red[t] = fmaxf(red[t], red[t + o]); __syncthreads(); }
  float mx = red[0]; __syncthreads();
  float ev = (t < S_) ? expf(sv - mx) : 0.f;
  red[t] = ev; __syncthreads();
  for (int o = 128; o; o >>= 1) { if (t < o) red[t] += red[t + o]; __syncthreads(); }
  float inv = 1.f / red[0];
  p[t] = ev * inv;
  __syncthreads();

  // ctx: thread t owns elements 2t, 2t+1
  const float* eo = enc_out + (size_t)b * S_ * H_ + (t << 1);
  float ax = 0.f, ay = 0.f;
  for (int i = 0; i < S_; ++i) {
    float pi = p[i];
    float2 v = *(const float2*)(eo + (size_t)i * H_);
    ax += pi * v.x; ay += pi * v.y;
  }
  float* cd = Cmat + ((size_t)td * B_ + b) * (2 * H_) + (t << 1);
  cd[0] = ax; cd[1] = ay;
}

// ---------------- tiled fp32 GEMM: C[m][n] = act(sum_k A[m][k]*Bw[n][k] + bias[n]) ----------------
template<int MODE>
__launch_bounds__(WGS)
__global__ void gemm_bt(const float* __restrict__ A,
                        const int* __restrict__ idx,
                        const float* __restrict__ Bw,
                        const float* __restrict__ bias,
                        float* __restrict__ Cdst,
                        int M, int N, int K)
{
  const int BM = 64, BN = 64, BK = 16;
  __shared__ float As[BK][BM];
  __shared__ float Bs[BK][BN];
  __shared__ int toks[BM];
  const int m0 = blockIdx.y * BM, n0 = blockIdx.x * BN;
  const int t = threadIdx.x;
  const int tx = t & 15, ty = t >> 4;
  float acc[4][4] = {{0.f}};

  if (MODE <= 1) {
    if (t < BM) {
      int m = m0 + t;
      int tok = 0;
      if (m < M) {
        int bidx = m & 31, srow = m >> 5;
        tok = (MODE == 0) ? idx[bidx * S_ + srow] : idx[bidx * L_ + srow];
      }
      toks[t] = tok;
    }
    __syncthreads();
  }

  const int row = t >> 2, kk = (t & 3) * 4;
  for (int k0 = 0; k0 < K; k0 += BK) {
    {
      int m = m0 + row;
      float4 v = {0.f, 0.f, 0.f, 0.f};
      if (m < M) {
        const float* src = (MODE <= 1) ? (A + (size_t)toks[row] * K + k0 + kk)
                                       : (A + (size_t)m * K + k0 + kk);
        v = *(const float4*)src;
      }
      As[kk][row] = v.x; As[kk + 1][row] = v.y; As[kk + 2][row] = v.z; As[kk + 3][row] = v.w;
      int n = n0 + row;
      float4 wv = {0.f, 0.f, 0.f, 0.f};
      if (n < N) wv = *(const float4*)(Bw + (size_t)n * K + k0 + kk);
      Bs[kk][row] = wv.x; Bs[kk + 1][row] = wv.y; Bs[kk + 2][row] = wv.z; Bs[kk + 3][row] = wv.w;
    }
    __syncthreads();
    #pragma unroll
    for (int k = 0; k < BK; ++k) {
      float a[4], bq[4];
      *(float4*)a  = *(const float4*)&As[k][ty * 4];
      *(float4*)bq = *(const float4*)&Bs[k][tx * 4];
      #pragma unroll
      for (int i = 0; i < 4; ++i)
        #pragma unroll
        for (int jj = 0; jj < 4; ++jj)
          acc[i][jj] += a[i] * bq[jj];
    }
    __syncthreads();
  }

  #pragma unroll
  for (int i = 0; i < 4; ++i) {
    int m = m0 + ty * 4 + i;
    if (m >= M) continue;
    #pragma unroll
    for (int jj = 0; jj < 4; ++jj) {
      int n = n0 + tx * 4 + jj;
      if (n >= N) continue;
      float v = acc[i][jj] + bias[n];
      if (MODE == 2) v = fmaxf(v, 0.f);
      if (MODE == 3) {
        int bidx = m & 31, td = m >> 5;
        Cdst[((size_t)bidx * TD_ + td) * (size_t)VS_ + n] = v;
      } else {
        Cdst[(size_t)m * N + n] = v;
      }
    }
  }
}

// ---------------- launch ----------------
extern "C" void kernel_launch(void* const* d_in, const int* in_sizes, int n_in,
                              void* d_out, int out_size, void* d_ws, size_t ws_size,
                              hipStream_t stream) {
  const int*   method_code    = (const int*)d_in[0];
  const int*   method_summary = (const int*)d_in[1];
  const float* enc_emb = (const float*)d_in[3];
  const float* enc_Wih = (const float*)d_in[4];
  const float* enc_Whh = (const float*)d_in[5];
  const float* enc_bih = (const float*)d_in[6];
  const float* enc_bhh = (const float*)d_in[7];
  const float* dec_emb = (const float*)d_in[8];
  const float* dec_Wih = (const float*)d_in[9];
  const float* dec_Whh = (const float*)d_in[10];
  const float* dec_bih = (const float*)d_in[11];
  const float* dec_bhh = (const float*)d_in[12];
  const float* W1 = (const float*)d_in[13];
  const float* b1 = (const float*)d_in[14];
  const float* W2 = (const float*)d_in[15];
  const float* b2 = (const float*)d_in[16];

  float* ws      = (float*)d_ws;
  float* enc_gx  = ws + OFF_ENC_GX;
  float* dec_gx  = ws + OFF_DEC_GX;
  float* enc_out = ws + OFF_ENC_OUT;
  float* hbuf    = ws + OFF_HBUF;
  float* Cmat    = ws + OFF_CMAT;
  float* OUT1    = ws + OFF_OUT1;
  unsigned* bar  = (unsigned*)(ws + OFF_BAR);

  // reset state every call (graph replays): barrier counters + h0 = 0
  hipMemsetAsync(bar, 0, SZ_BAR * sizeof(unsigned), stream);
  hipMemsetAsync(hbuf, 0, SZ_HBUF * sizeof(float), stream);

  dim3 blk(WGS);
  // gx precompute (gather-GEMMs)
  gemm_bt<0><<<dim3(G3_ / 64, (S_ * B_) / 64), blk, 0, stream>>>(
      enc_emb, method_code, enc_Wih, enc_bih, enc_gx, S_ * B_, G3_, DE_);
  gemm_bt<1><<<dim3(G3_ / 64, (TD_ * B_ + 63) / 64), blk, 0, stream>>>(
      dec_emb, method_summary, dec_Wih, dec_bih, dec_gx, TD_ * B_, G3_, DE_);

  // persistent GRU chains (encoder + decoder)
  recurrence_kernel<<<NWG, blk, 0, stream>>>(enc_gx, dec_gx,
                                             enc_Whh, enc_bhh, dec_Whh, dec_bhh,
                                             enc_out, hbuf, Cmat, bar);

  // attention for all (td, b) in parallel
  attention_kernel<<<TD_ * B_, blk, 0, stream>>>(enc_out, Cmat);

  // output projection, batched over all 49*32 steps
  gemm_bt<2><<<dim3(H_ / 64, (TD_ * B_ + 63) / 64), blk, 0, stream>>>(
      Cmat, nullptr, W1, b1, OUT1, TD_ * B_, H_, 2 * H_);
  gemm_bt<3><<<dim3((VS_ + 63) / 64, (TD_ * B_ + 63) / 64), blk, 0, stream>>>(
      OUT1, nullptr, W2, b2, (float*)d_out, TD_ * B_, VS_, H_);
}

// Round 3
// 4316.344 us; speedup vs baseline: 3.5570x; 3.3115x over previous
//
#include <hip/hip_runtime.h>
#include <cmath>

#define WGS  256
#define NWGR 256         // recurrence workgroups (1 per CU)

// ---------------- sizes ----------------
#define B_   32
#define S_   200
#define L_   50
#define H_   512
#define DE_  256
#define VS_  30000
#define TD_  49          // L-1 decoder steps
#define G3_  1536        // 3*H

// ws layout (float offsets)
#define OFF_ENC_GX  ((size_t)0)                         // [200][32][1536]
#define SZ_ENC_GX   ((size_t)S_*B_*G3_)
#define OFF_DEC_GX  (OFF_ENC_GX + SZ_ENC_GX)            // [49][32][1536]
#define SZ_DEC_GX   ((size_t)TD_*B_*G3_)
#define OFF_ENC_OUT (OFF_DEC_GX + SZ_DEC_GX)            // [32][200][512]
#define SZ_ENC_OUT  ((size_t)B_*S_*H_)
#define OFF_HBUF    (OFF_ENC_OUT + SZ_ENC_OUT)          // [2][32][512]
#define SZ_HBUF     ((size_t)2*B_*H_)
#define OFF_CMAT    (OFF_HBUF + SZ_HBUF)                // [49][32][1024]
#define SZ_CMAT     ((size_t)TD_*B_*2*H_)
#define OFF_OUT1    (OFF_CMAT + SZ_CMAT)                // [1568][512]
#define SZ_OUT1     ((size_t)TD_*B_*H_)
#define OFF_BAR     (OFF_OUT1 + SZ_OUT1)                // flags[256*16]
#define SZ_BAR      ((size_t)(NWGR*16))                 // uints

// ---------------- all-to-all grid barrier ----------------
// Every WG release-stores its monotonic step counter to its own cacheline.
// Every thread t spins (RELAXED, agent-scope = sc0 sc1, bypasses stale L1/L2)
// on WG t's flag. No acquire fence anywhere -> no L2-wide invalidates; all
// cross-WG data (hbuf) is itself read/written via agent-scope relaxed atomics.
__device__ __forceinline__ void gbar(unsigned* __restrict__ flags,
                                     unsigned step, int w, int t) {
  __syncthreads();   // drains each wave's vmcnt(0): hbuf stores are at the
                     // coherence point before the flag is posted
  if (t == 0)
    __hip_atomic_store(&flags[w * 16], step, __ATOMIC_RELEASE,
                       __HIP_MEMORY_SCOPE_AGENT);
  while (__hip_atomic_load(&flags[t * 16], __ATOMIC_RELAXED,
                           __HIP_MEMORY_SCOPE_AGENT) < step) { }
  __syncthreads();
}

// ---------------- persistent GRU-chain kernel ----------------
// 256 WGs: WG = (jg in [0,128) owning 4 j-values, bg in [0,2) owning 16 batches).
// Thread t: kh = t>>6 (k-quarter), b16 = (t>>2)&15, jl = t&3.
// Whh slice + h tile live in LDS; cross-WG h exchange via sc1 relaxed atomics.
__global__ __launch_bounds__(WGS)
void recurrence_kernel(const float* __restrict__ enc_gx,
                       const float* __restrict__ dec_gx,
                       const float* __restrict__ eWhh, const float* __restrict__ eBhh,
                       const float* __restrict__ dWhh, const float* __restrict__ dBhh,
                       float* __restrict__ enc_out,
                       float* __restrict__ hbuf,
                       float* __restrict__ Cmat,
                       unsigned* __restrict__ flags)
{
  __shared__ float wlds[12 * 516];   // 24.75 KB: rows g*4+jl, padded stride 516
  __shared__ float hlds[16 * 516];   // 33 KB: 16 batches x full h row
  __shared__ float red[768];         // partial dots [g][b16][jl][kh]

  const int t   = threadIdx.x;
  const int w   = blockIdx.x;
  const int jg  = w >> 1;
  const int bg  = w & 1;
  const int kh  = t >> 6;
  const int b16 = (t >> 2) & 15;
  const int jl  = t & 3;
  const int b   = (bg << 4) + b16;
  const int j   = (jg << 2) + jl;

  float bias_r = 0.f, bias_z = 0.f, bias_n = 0.f;
  if (t < 64) {        // tail threads: kh==0 -> same (b16,jl) mapping
    bias_r = eBhh[j]; bias_z = eBhh[H_ + j]; bias_n = eBhh[2 * H_ + j];
  }

  // stage encoder Whh slice into LDS (cached loads; LDS is fence-immune)
  for (int i = t; i < 12 * 128; i += WGS) {
    int row = i >> 7, k4 = (i & 127) << 2;
    int g = row >> 2, rl = row & 3;
    float4 v = *(const float4*)(eWhh + ((size_t)(g * H_ + (jg << 2) + rl)) * H_ + k4);
    *(float4*)&wlds[row * 516 + k4] = v;
  }
  __syncthreads();

  unsigned step = 0;
  int cur = 0;

  for (int s = 0; s < S_ + TD_; ++s) {
    const bool enc = (s < S_);
    if (s == S_) {   // switch to decoder weights (prev gbar synced everyone)
      for (int i = t; i < 12 * 128; i += WGS) {
        int row = i >> 7, k4 = (i & 127) << 2;
        int g = row >> 2, rl = row & 3;
        float4 v = *(const float4*)(dWhh + ((size_t)(g * H_ + (jg << 2) + rl)) * H_ + k4);
        *(float4*)&wlds[row * 516 + k4] = v;
      }
      if (t < 64) { bias_r = dBhh[j]; bias_z = dBhh[H_ + j]; bias_n = dBhh[2 * H_ + j]; }
    }

    // stage h[cur] for our 16 batches: agent-scope relaxed 8B loads (sc0 sc1)
    {
      const unsigned long long* hsrc =
          (const unsigned long long*)hbuf + (size_t)cur * (B_ * H_ / 2);
      for (int i = t; i < 16 * 256; i += WGS) {
        int bb = i >> 8, kp = i & 255;
        unsigned long long v = __hip_atomic_load(
            (unsigned long long*)&hsrc[(size_t)((bg << 4) + bb) * 256 + kp],
            __ATOMIC_RELAXED, __HIP_MEMORY_SCOPE_AGENT);
        float2 f;
        f.x = __uint_as_float((unsigned)v);
        f.y = __uint_as_float((unsigned)(v >> 32));
        *(float2*)&hlds[bb * 516 + (kp << 1)] = f;
      }
    }
    // prefetch gx for the tail (read-only data, normal cached loads)
    float gxr = 0.f, gxz = 0.f, gxn = 0.f;
    if (t < 64) {
      const float* gx = enc ? (enc_gx + ((size_t)s * B_ + b) * G3_)
                            : (dec_gx + ((size_t)(s - S_) * B_ + b) * G3_);
      gxr = gx[j]; gxz = gx[H_ + j]; gxn = gx[2 * H_ + j];
    }
    __syncthreads();

    // k-quarter partial dot products (all from LDS, conflict-free b128)
    {
      const float* hrow = &hlds[b16 * 516 + (kh << 7)];
      const float* wr   = &wlds[(jl     ) * 516 + (kh << 7)];
      const float* wz   = &wlds[(4 + jl ) * 516 + (kh << 7)];
      const float* wn   = &wlds[(8 + jl ) * 516 + (kh << 7)];
      float ar = 0.f, az = 0.f, an = 0.f;
      #pragma unroll 8
      for (int k = 0; k < 128; k += 4) {
        float4 hv = *(const float4*)(hrow + k);
        float4 rv = *(const float4*)(wr + k);
        float4 zv = *(const float4*)(wz + k);
        float4 nv = *(const float4*)(wn + k);
        ar += hv.x * rv.x + hv.y * rv.y + hv.z * rv.z + hv.w * rv.w;
        az += hv.x * zv.x + hv.y * zv.y + hv.z * zv.z + hv.w * zv.w;
        an += hv.x * nv.x + hv.y * nv.y + hv.z * nv.z + hv.w * nv.w;
      }
      int base = ((b16 << 2) + jl) * 4 + kh;   // = t's (b16,jl) slot
      red[base      ] = ar;
      red[base + 256] = az;
      red[base + 512] = an;
    }
    __syncthreads();

    // tail: combine k-quarters, gate math, state update
    if (t < 64) {
      float4 r4 = *(const float4*)&red[t * 4];
      float4 z4 = *(const float4*)&red[t * 4 + 256];
      float4 n4 = *(const float4*)&red[t * 4 + 512];
      float ar = ((r4.x + r4.y) + r4.z) + r4.w;
      float az = ((z4.x + z4.y) + z4.z) + z4.w;
      float an = ((n4.x + n4.y) + n4.z) + n4.w;
      float rg = 1.f / (1.f + expf(-(gxr + ar + bias_r)));
      float zg = 1.f / (1.f + expf(-(gxz + az + bias_z)));
      float ng = tanhf(gxn + rg * (an + bias_n));
      float hn = (1.f - zg) * ng + zg * hlds[b16 * 516 + j];
      __hip_atomic_store(hbuf + (size_t)(cur ^ 1) * (B_ * H_) + (b << 9) + j, hn,
                         __ATOMIC_RELAXED, __HIP_MEMORY_SCOPE_AGENT);
      if (enc) enc_out[((size_t)b * S_ + s) * H_ + j] = hn;
      else     Cmat[((size_t)(s - S_) * B_ + b) * (2 * H_) + H_ + j] = hn;
    }
    cur ^= 1;
    if (s < S_ + TD_ - 1) { ++step; gbar(flags, step, w, t); }
  }
}

// ---------------- attention kernel: one WG per (td, b) ----------------
__global__ __launch_bounds__(WGS)
void attention_kernel(const float* __restrict__ enc_out,
                      float* __restrict__ Cmat)
{
  const int task = blockIdx.x;          // td*32 + b
  const int td = task >> 5, b = task & 31;
  const int t = threadIdx.x;
  const float* h = Cmat + ((size_t)td * B_ + b) * (2 * H_) + H_;

  __shared__ float red[WGS];
  __shared__ float p[WGS];              // 200 used

  float sv = -1e30f;
  if (t < S_) {
    const float* eo = enc_out + ((size_t)b * S_ + t) * H_;
    float acc = 0.f;
    #pragma unroll 4
    for (int k = 0; k < H_; k += 4) {
      float4 e = *(const float4*)(eo + k);
      float4 hv = *(const float4*)(h + k);
      acc += e.x * hv.x + e.y * hv.y + e.z * hv.z + e.w * hv.w;
    }
    sv = acc;
  }
  red[t] = sv; __syncthreads();
  for (int o = 128; o; o >>= 1) { if (t < o) red[t] = fmaxf(red[t], red[t + o]); __syncthreads(); }
  float mx = red[0]; __syncthreads();
  float ev = (t < S_) ? expf(sv - mx) : 0.f;
  red[t] = ev; __syncthreads();
  for (int o = 128; o; o >>= 1) { if (t < o) red[t] += red[t + o]; __syncthreads(); }
  float inv = 1.f / red[0];
  p[t] = ev * inv;
  __syncthreads();

  const float* eo = enc_out + (size_t)b * S_ * H_ + (t << 1);
  float ax = 0.f, ay = 0.f;
  for (int i = 0; i < S_; ++i) {
    float pi = p[i];
    float2 v = *(const float2*)(eo + (size_t)i * H_);
    ax += pi * v.x; ay += pi * v.y;
  }
  float* cd = Cmat + ((size_t)td * B_ + b) * (2 * H_) + (t << 1);
  cd[0] = ax; cd[1] = ay;
}

// ---------------- tiled fp32 GEMM: C[m][n] = act(sum_k A[m][k]*Bw[n][k] + bias[n]) ----------------
template<int MODE>
__launch_bounds__(WGS)
__global__ void gemm_bt(const float* __restrict__ A,
                        const int* __restrict__ idx,
                        const float* __restrict__ Bw,
                        const float* __restrict__ bias,
                        float* __restrict__ Cdst,
                        int M, int N, int K)
{
  const int BM = 64, BN = 64, BK = 16;
  __shared__ float As[BK][BM];
  __shared__ float Bs[BK][BN];
  __shared__ int toks[BM];
  const int m0 = blockIdx.y * BM, n0 = blockIdx.x * BN;
  const int t = threadIdx.x;
  const int tx = t & 15, ty = t >> 4;
  float acc[4][4] = {{0.f}};

  if (MODE <= 1) {
    if (t < BM) {
      int m = m0 + t;
      int tok = 0;
      if (m < M) {
        int bidx = m & 31, srow = m >> 5;
        tok = (MODE == 0) ? idx[bidx * S_ + srow] : idx[bidx * L_ + srow];
      }
      toks[t] = tok;
    }
    __syncthreads();
  }

  const int row = t >> 2, kk = (t & 3) * 4;
  for (int k0 = 0; k0 < K; k0 += BK) {
    {
      int m = m0 + row;
      float4 v = {0.f, 0.f, 0.f, 0.f};
      if (m < M) {
        const float* src = (MODE <= 1) ? (A + (size_t)toks[row] * K + k0 + kk)
                                       : (A + (size_t)m * K + k0 + kk);
        v = *(const float4*)src;
      }
      As[kk][row] = v.x; As[kk + 1][row] = v.y; As[kk + 2][row] = v.z; As[kk + 3][row] = v.w;
      int n = n0 + row;
      float4 wv = {0.f, 0.f, 0.f, 0.f};
      if (n < N) wv = *(const float4*)(Bw + (size_t)n * K + k0 + kk);
      Bs[kk][row] = wv.x; Bs[kk + 1][row] = wv.y; Bs[kk + 2][row] = wv.z; Bs[kk + 3][row] = wv.w;
    }
    __syncthreads();
    #pragma unroll
    for (int k = 0; k < BK; ++k) {
      float a[4], bq[4];
      *(float4*)a  = *(const float4*)&As[k][ty * 4];
      *(float4*)bq = *(const float4*)&Bs[k][tx * 4];
      #pragma unroll
      for (int i = 0; i < 4; ++i)
        #pragma unroll
        for (int jj = 0; jj < 4; ++jj)
          acc[i][jj] += a[i] * bq[jj];
    }
    __syncthreads();
  }

  #pragma unroll
  for (int i = 0; i < 4; ++i) {
    int m = m0 + ty * 4 + i;
    if (m >= M) continue;
    #pragma unroll
    for (int jj = 0; jj < 4; ++jj) {
      int n = n0 + tx * 4 + jj;
      if (n >= N) continue;
      float v = acc[i][jj] + bias[n];
      if (MODE == 2) v = fmaxf(v, 0.f);
      if (MODE == 3) {
        int bidx = m & 31, td = m >> 5;
        Cdst[((size_t)bidx * TD_ + td) * (size_t)VS_ + n] = v;
      } else {
        Cdst[(size_t)m * N + n] = v;
      }
    }
  }
}

// ---------------- launch ----------------
extern "C" void kernel_launch(void* const* d_in, const int* in_sizes, int n_in,
                              void* d_out, int out_size, void* d_ws, size_t ws_size,
                              hipStream_t stream) {
  const int*   method_code    = (const int*)d_in[0];
  const int*   method_summary = (const int*)d_in[1];
  const float* enc_emb = (const float*)d_in[3];
  const float* enc_Wih = (const float*)d_in[4];
  const float* enc_Whh = (const float*)d_in[5];
  const float* enc_bih = (const float*)d_in[6];
  const float* enc_bhh = (const float*)d_in[7];
  const float* dec_emb = (const float*)d_in[8];
  const float* dec_Wih = (const float*)d_in[9];
  const float* dec_Whh = (const float*)d_in[10];
  const float* dec_bih = (const float*)d_in[11];
  const float* dec_bhh = (const float*)d_in[12];
  const float* W1 = (const float*)d_in[13];
  const float* b1 = (const float*)d_in[14];
  const float* W2 = (const float*)d_in[15];
  const float* b2 = (const float*)d_in[16];

  float* ws      = (float*)d_ws;
  float* enc_gx  = ws + OFF_ENC_GX;
  float* dec_gx  = ws + OFF_DEC_GX;
  float* enc_out = ws + OFF_ENC_OUT;
  float* hbuf    = ws + OFF_HBUF;
  float* Cmat    = ws + OFF_CMAT;
  float* OUT1    = ws + OFF_OUT1;
  unsigned* bar  = (unsigned*)(ws + OFF_BAR);

  // reset state every call (graph replays): barrier flags + h0 = 0
  hipMemsetAsync(bar, 0, SZ_BAR * sizeof(unsigned), stream);
  hipMemsetAsync(hbuf, 0, SZ_HBUF * sizeof(float), stream);

  dim3 blk(WGS);
  // gx precompute (gather-GEMMs)
  gemm_bt<0><<<dim3(G3_ / 64, (S_ * B_) / 64), blk, 0, stream>>>(
      enc_emb, method_code, enc_Wih, enc_bih, enc_gx, S_ * B_, G3_, DE_);
  gemm_bt<1><<<dim3(G3_ / 64, (TD_ * B_ + 63) / 64), blk, 0, stream>>>(
      dec_emb, method_summary, dec_Wih, dec_bih, dec_gx, TD_ * B_, G3_, DE_);

  // persistent GRU chains (encoder + decoder), 256 WGs
  recurrence_kernel<<<NWGR, blk, 0, stream>>>(enc_gx, dec_gx,
                                              enc_Whh, enc_bhh, dec_Whh, dec_bhh,
                                              enc_out, hbuf, Cmat, bar);

  // attention for all (td, b) in parallel
  attention_kernel<<<TD_ * B_, blk, 0, stream>>>(enc_out, Cmat);

  // output projection, batched over all 49*32 steps
  gemm_bt<2><<<dim3(H_ / 64, (TD_ * B_ + 63) / 64), blk, 0, stream>>>(
      Cmat, nullptr, W1, b1, OUT1, TD_ * B_, H_, 2 * H_);
  gemm_bt<3><<<dim3((VS_ + 63) / 64, (TD_ * B_ + 63) / 64), blk, 0, stream>>>(
      OUT1, nullptr, W2, b2, (float*)d_out, TD_ * B_, VS_, H_);
}

// Round 4
// 2772.038 us; speedup vs baseline: 5.5386x; 1.5571x over previous
//
#include <hip/hip_runtime.h>
#include <cmath>

#define WGS  256
#define NWGR 256         // recurrence workgroups (1 per CU)

typedef float    f32x4 __attribute__((ext_vector_type(4)));
typedef unsigned u32x4 __attribute__((ext_vector_type(4)));

// ---------------- sizes ----------------
#define B_   32
#define S_   200
#define L_   50
#define H_   512
#define DE_  256
#define VS_  30000
#define TD_  49          // L-1 decoder steps
#define G3_  1536        // 3*H

// ws layout (float offsets)
#define OFF_ENC_GX  ((size_t)0)                         // [200][32][1536]
#define SZ_ENC_GX   ((size_t)S_*B_*G3_)
#define OFF_DEC_GX  (OFF_ENC_GX + SZ_ENC_GX)            // [49][32][1536]
#define SZ_DEC_GX   ((size_t)TD_*B_*G3_)
#define OFF_ENC_OUT (OFF_DEC_GX + SZ_DEC_GX)            // [32][200][512]
#define SZ_ENC_OUT  ((size_t)B_*S_*H_)
#define OFF_HBUF    (OFF_ENC_OUT + SZ_ENC_OUT)          // [2][32][512]
#define SZ_HBUF     ((size_t)2*B_*H_)
#define OFF_CMAT    (OFF_HBUF + SZ_HBUF)                // [49][32][1024]
#define SZ_CMAT     ((size_t)TD_*B_*2*H_)
#define OFF_OUT1    (OFF_CMAT + SZ_CMAT)                // [1568][512]
#define SZ_OUT1     ((size_t)TD_*B_*H_)
#define OFF_BAR     (OFF_OUT1 + SZ_OUT1)                // flags[256] packed
#define SZ_BAR      ((size_t)NWGR)                      // uints

// LDS geometry: rows padded to 548 floats; 8 k-blocks of 64 floats @ stride 68
#define RSTR 548
#define KBLK 68

// ---------------- grid barrier: packed flags, wave-0 vector poll ----------------
__device__ __forceinline__ void gbar(unsigned* __restrict__ flags,
                                     unsigned step, int w, int t) {
  __syncthreads();   // all waves' tracked stores (incl. atomic h stores) drained
  if (t == 0) {
    asm volatile("s_waitcnt vmcnt(0)" ::: "memory");
    const unsigned* fp = flags + w;
    asm volatile("global_store_dword %0, %1, off sc0 sc1"
                 :: "v"(fp), "v"(step) : "memory");
  }
  if (t < 64) {      // wave 0: each lane covers 4 flags -> 1 load = all 256
    const unsigned* base = flags + (t << 2);
    while (true) {
      u32x4 v;
      asm volatile("global_load_dwordx4 %0, %1, off sc0 sc1"
                   : "=v"(v) : "v"(base) : "memory");
      asm volatile("s_waitcnt vmcnt(0)" ::: "memory");
      unsigned mn = min(min((unsigned)v.x, (unsigned)v.y),
                        min((unsigned)v.z, (unsigned)v.w));
      if (__all(mn >= step)) break;
      __builtin_amdgcn_s_sleep(2);
    }
  }
  __syncthreads();
}

// ---------------- persistent GRU-chain kernel ----------------
// 256 WGs: WG = (jg in [0,128) owning 4 j, bg in [0,2) owning 16 batches).
// Compute thread t: kq = t>>5 (8 k-blocks of 64), bp = (t>>2)&7 (batch pair), jl = t&3.
// Tail thread t<64: b16 = t>>2, jl = t&3.
__global__ __launch_bounds__(WGS)
void recurrence_kernel(const float* __restrict__ enc_gx,
                       const float* __restrict__ dec_gx,
                       const float* __restrict__ eWhh, const float* __restrict__ eBhh,
                       const float* __restrict__ dWhh, const float* __restrict__ dBhh,
                       float* __restrict__ enc_out,
                       float* __restrict__ hbuf,
                       float* __restrict__ Cmat,
                       unsigned* __restrict__ flags)
{
  __shared__ float wlds[12 * RSTR];   // 26304 B
  __shared__ float hlds[16 * RSTR];   // 35072 B
  __shared__ float red[768];          //  3072 B   (total 64448 <= 64K)

  const int t  = threadIdx.x;
  const int w  = blockIdx.x;
  const int jg = w >> 1;
  const int bg = w & 1;
  const int kq = t >> 5;
  const int bp = (t >> 2) & 7;
  const int jl = t & 3;
  const int b16 = t >> 2;                 // tail mapping (t<64)
  const int j   = (jg << 2) + (t & 3);
  const int b   = (bg << 4) + b16;

  float bias_r = 0.f, bias_z = 0.f, bias_n = 0.f;
  if (t < 64) { bias_r = eBhh[j]; bias_z = eBhh[H_ + j]; bias_n = eBhh[2 * H_ + j]; }

  // stage a Whh slice (12 rows x 512) into padded LDS layout
  auto stage_w = [&](const float* __restrict__ W) {
    for (int i = t; i < 12 * 128; i += WGS) {
      int row = i >> 7, kf = i & 127;
      int g = row >> 2, rl = row & 3;
      f32x4 v = *(const f32x4*)(W + ((size_t)(g * H_ + (jg << 2) + rl)) * H_ + (kf << 2));
      *(f32x4*)&wlds[row * RSTR + (kf >> 4) * KBLK + ((kf & 15) << 2)] = v;
    }
  };
  stage_w(eWhh);

  unsigned step = 0;
  int cur = 0;

  for (int s = 0; s < S_ + TD_; ++s) {
    const bool enc = (s < S_);
    if (s == S_) {   // decoder weights (prev gbar's trailing syncthreads protects wlds)
      stage_w(dWhh);
      if (t < 64) { bias_r = dBhh[j]; bias_z = dBhh[H_ + j]; bias_n = dBhh[2 * H_ + j]; }
    }

    // gx for the tail (issued early; normal cached loads overlap staging)
    float gxr = 0.f, gxz = 0.f, gxn = 0.f;
    if (t < 64) {
      const float* gx = enc ? (enc_gx + ((size_t)s * B_ + b) * G3_)
                            : (dec_gx + ((size_t)(s - S_) * B_ + b) * G3_);
      gxr = gx[j]; gxz = gx[H_ + j]; gxn = gx[2 * H_ + j];
    }

    // ---- stage h[cur] (16 batches x 512): 8 pipelined sc0sc1 16B loads ----
    {
      const f32x4* hsrc = (const f32x4*)hbuf + (size_t)cur * 4096 + (size_t)bg * 2048;
      f32x4 v0, v1, v2, v3, v4, v5, v6, v7;
      const f32x4* p;
      p = hsrc + 0 * 256 + t; asm volatile("global_load_dwordx4 %0, %1, off sc0 sc1" : "=v"(v0) : "v"(p) : "memory");
      p = hsrc + 1 * 256 + t; asm volatile("global_load_dwordx4 %0, %1, off sc0 sc1" : "=v"(v1) : "v"(p) : "memory");
      p = hsrc + 2 * 256 + t; asm volatile("global_load_dwordx4 %0, %1, off sc0 sc1" : "=v"(v2) : "v"(p) : "memory");
      p = hsrc + 3 * 256 + t; asm volatile("global_load_dwordx4 %0, %1, off sc0 sc1" : "=v"(v3) : "v"(p) : "memory");
      p = hsrc + 4 * 256 + t; asm volatile("global_load_dwordx4 %0, %1, off sc0 sc1" : "=v"(v4) : "v"(p) : "memory");
      p = hsrc + 5 * 256 + t; asm volatile("global_load_dwordx4 %0, %1, off sc0 sc1" : "=v"(v5) : "v"(p) : "memory");
      p = hsrc + 6 * 256 + t; asm volatile("global_load_dwordx4 %0, %1, off sc0 sc1" : "=v"(v6) : "v"(p) : "memory");
      p = hsrc + 7 * 256 + t; asm volatile("global_load_dwordx4 %0, %1, off sc0 sc1" : "=v"(v7) : "v"(p) : "memory");
      asm volatile("s_waitcnt vmcnt(0)" ::: "memory");
      #define HW(jj, vv) { int f = jj * 256 + t; int bb = f >> 7, kf = f & 127; \
        *(f32x4*)&hlds[bb * RSTR + (kf >> 4) * KBLK + ((kf & 15) << 2)] = vv; }
      HW(0, v0) HW(1, v1) HW(2, v2) HW(3, v3) HW(4, v4) HW(5, v5) HW(6, v6) HW(7, v7)
      #undef HW
    }
    __syncthreads();

    // ---- partial dots: 2 batches x 3 gates x 64 k per thread ----
    {
      const float* wr0 = &wlds[(0 + jl) * RSTR + kq * KBLK];
      const float* wz0 = &wlds[(4 + jl) * RSTR + kq * KBLK];
      const float* wn0 = &wlds[(8 + jl) * RSTR + kq * KBLK];
      const float* h0  = &hlds[(bp * 2 + 0) * RSTR + kq * KBLK];
      const float* h1  = &hlds[(bp * 2 + 1) * RSTR + kq * KBLK];
      float a0r = 0.f, a0z = 0.f, a0n = 0.f, a1r = 0.f, a1z = 0.f, a1n = 0.f;
      #pragma unroll
      for (int i = 0; i < 16; ++i) {
        f32x4 rv = *(const f32x4*)(wr0 + i * 4);
        f32x4 zv = *(const f32x4*)(wz0 + i * 4);
        f32x4 nv = *(const f32x4*)(wn0 + i * 4);
        f32x4 hv0 = *(const f32x4*)(h0 + i * 4);
        f32x4 hv1 = *(const f32x4*)(h1 + i * 4);
        a0r += hv0.x * rv.x + hv0.y * rv.y + hv0.z * rv.z + hv0.w * rv.w;
        a0z += hv0.x * zv.x + hv0.y * zv.y + hv0.z * zv.z + hv0.w * zv.w;
        a0n += hv0.x * nv.x + hv0.y * nv.y + hv0.z * nv.z + hv0.w * nv.w;
        a1r += hv1.x * rv.x + hv1.y * rv.y + hv1.z * rv.z + hv1.w * rv.w;
        a1z += hv1.x * zv.x + hv1.y * zv.y + hv1.z * zv.z + hv1.w * zv.w;
        a1n += hv1.x * nv.x + hv1.y * nv.y + hv1.z * nv.z + hv1.w * nv.w;
      }
      // fold kq pairs (lanes differ in bit 5 within the wave)
      a0r += __shfl_xor(a0r, 32); a0z += __shfl_xor(a0z, 32); a0n += __shfl_xor(a0n, 32);
      a1r += __shfl_xor(a1r, 32); a1z += __shfl_xor(a1z, 32); a1n += __shfl_xor(a1n, 32);
      if ((t & 32) == 0) {
        float* rd = &red[(t >> 6) * 192 + (bp * 4 + jl) * 6];
        rd[0] = a0r; rd[1] = a0z; rd[2] = a0n; rd[3] = a1r; rd[4] = a1z; rd[5] = a1n;
      }
    }
    __syncthreads();

    // ---- tail: combine 4 wave-partials, gate math, state update ----
    if (t < 64) {
      const int bpp = b16 >> 1, bi = b16 & 1;
      const int rb = (bpp * 4 + (t & 3)) * 6 + bi * 3;
      float ar = red[rb] + red[192 + rb] + red[384 + rb] + red[576 + rb];
      float az = red[rb + 1] + red[192 + rb + 1] + red[384 + rb + 1] + red[576 + rb + 1];
      float an = red[rb + 2] + red[192 + rb + 2] + red[384 + rb + 2] + red[576 + rb + 2];
      float rg = 1.f / (1.f + expf(-(gxr + ar + bias_r)));
      float zg = 1.f / (1.f + expf(-(gxz + az + bias_z)));
      float ng = tanhf(gxn + rg * (an + bias_n));
      float hprev = hlds[b16 * RSTR + (j >> 6) * KBLK + (j & 63)];
      float hn = (1.f - zg) * ng + zg * hprev;
      __hip_atomic_store(hbuf + (size_t)(cur ^ 1) * (B_ * H_) + (b << 9) + j, hn,
                         __ATOMIC_RELAXED, __HIP_MEMORY_SCOPE_AGENT);
      if (enc) enc_out[((size_t)b * S_ + s) * H_ + j] = hn;
      else     Cmat[((size_t)(s - S_) * B_ + b) * (2 * H_) + H_ + j] = hn;
    }
    cur ^= 1;
    if (s < S_ + TD_ - 1) { ++step; gbar(flags, step, w, t); }
  }
}

// ---------------- attention kernel: one WG per (td, b) ----------------
__global__ __launch_bounds__(WGS)
void attention_kernel(const float* __restrict__ enc_out,
                      float* __restrict__ Cmat)
{
  const int task = blockIdx.x;          // td*32 + b
  const int td = task >> 5, b = task & 31;
  const int t = threadIdx.x;
  const float* h = Cmat + ((size_t)td * B_ + b) * (2 * H_) + H_;

  __shared__ float red[WGS];
  __shared__ float p[WGS];              // 200 used

  float sv = -1e30f;
  if (t < S_) {
    const float* eo = enc_out + ((size_t)b * S_ + t) * H_;
    float acc = 0.f;
    #pragma unroll 4
    for (int k = 0; k < H_; k += 4) {
      float4 e = *(const float4*)(eo + k);
      float4 hv = *(const float4*)(h + k);
      acc += e.x * hv.x + e.y * hv.y + e.z * hv.z + e.w * hv.w;
    }
    sv = acc;
  }
  red[t] = sv; __syncthreads();
  for (int o = 128; o; o >>= 1) { if (t < o) red[t] = fmaxf(red[t], red[t + o]); __syncthreads(); }
  float mx = red[0]; __syncthreads();
  float ev = (t < S_) ? expf(sv - mx) : 0.f;
  red[t] = ev; __syncthreads();
  for (int o = 128; o; o >>= 1) { if (t < o) red[t] += red[t + o]; __syncthreads(); }
  float inv = 1.f / red[0];
  p[t] = ev * inv;
  __syncthreads();

  const float* eo = enc_out + (size_t)b * S_ * H_ + (t << 1);
  float ax = 0.f, ay = 0.f;
  for (int i = 0; i < S_; ++i) {
    float pi = p[i];
    float2 v = *(const float2*)(eo + (size_t)i * H_);
    ax += pi * v.x; ay += pi * v.y;
  }
  float* cd = Cmat + ((size_t)td * B_ + b) * (2 * H_) + (t << 1);
  cd[0] = ax; cd[1] = ay;
}

// ---------------- tiled fp32 GEMM: C[m][n] = act(sum_k A[m][k]*Bw[n][k] + bias[n]) ----------------
template<int MODE>
__launch_bounds__(WGS)
__global__ void gemm_bt(const float* __restrict__ A,
                        const int* __restrict__ idx,
                        const float* __restrict__ Bw,
                        const float* __restrict__ bias,
                        float* __restrict__ Cdst,
                        int M, int N, int K)
{
  const int BM = 64, BN = 64, BK = 16;
  __shared__ float As[BK][BM];
  __shared__ float Bs[BK][BN];
  __shared__ int toks[BM];
  const int m0 = blockIdx.y * BM, n0 = blockIdx.x * BN;
  const int t = threadIdx.x;
  const int tx = t & 15, ty = t >> 4;
  float acc[4][4] = {{0.f}};

  if (MODE <= 1) {
    if (t < BM) {
      int m = m0 + t;
      int tok = 0;
      if (m < M) {
        int bidx = m & 31, srow = m >> 5;
        tok = (MODE == 0) ? idx[bidx * S_ + srow] : idx[bidx * L_ + srow];
      }
      toks[t] = tok;
    }
    __syncthreads();
  }

  const int row = t >> 2, kk = (t & 3) * 4;
  for (int k0 = 0; k0 < K; k0 += BK) {
    {
      int m = m0 + row;
      float4 v = {0.f, 0.f, 0.f, 0.f};
      if (m < M) {
        const float* src = (MODE <= 1) ? (A + (size_t)toks[row] * K + k0 + kk)
                                       : (A + (size_t)m * K + k0 + kk);
        v = *(const float4*)src;
      }
      As[kk][row] = v.x; As[kk + 1][row] = v.y; As[kk + 2][row] = v.z; As[kk + 3][row] = v.w;
      int n = n0 + row;
      float4 wv = {0.f, 0.f, 0.f, 0.f};
      if (n < N) wv = *(const float4*)(Bw + (size_t)n * K + k0 + kk);
      Bs[kk][row] = wv.x; Bs[kk + 1][row] = wv.y; Bs[kk + 2][row] = wv.z; Bs[kk + 3][row] = wv.w;
    }
    __syncthreads();
    #pragma unroll
    for (int k = 0; k < BK; ++k) {
      float a[4], bq[4];
      *(float4*)a  = *(const float4*)&As[k][ty * 4];
      *(float4*)bq = *(const float4*)&Bs[k][tx * 4];
      #pragma unroll
      for (int i = 0; i < 4; ++i)
        #pragma unroll
        for (int jj = 0; jj < 4; ++jj)
          acc[i][jj] += a[i] * bq[jj];
    }
    __syncthreads();
  }

  #pragma unroll
  for (int i = 0; i < 4; ++i) {
    int m = m0 + ty * 4 + i;
    if (m >= M) continue;
    #pragma unroll
    for (int jj = 0; jj < 4; ++jj) {
      int n = n0 + tx * 4 + jj;
      if (n >= N) continue;
      float v = acc[i][jj] + bias[n];
      if (MODE == 2) v = fmaxf(v, 0.f);
      if (MODE == 3) {
        int bidx = m & 31, td = m >> 5;
        Cdst[((size_t)bidx * TD_ + td) * (size_t)VS_ + n] = v;
      } else {
        Cdst[(size_t)m * N + n] = v;
      }
    }
  }
}

// ---------------- launch ----------------
extern "C" void kernel_launch(void* const* d_in, const int* in_sizes, int n_in,
                              void* d_out, int out_size, void* d_ws, size_t ws_size,
                              hipStream_t stream) {
  const int*   method_code    = (const int*)d_in[0];
  const int*   method_summary = (const int*)d_in[1];
  const float* enc_emb = (const float*)d_in[3];
  const float* enc_Wih = (const float*)d_in[4];
  const float* enc_Whh = (const float*)d_in[5];
  const float* enc_bih = (const float*)d_in[6];
  const float* enc_bhh = (const float*)d_in[7];
  const float* dec_emb = (const float*)d_in[8];
  const float* dec_Wih = (const float*)d_in[9];
  const float* dec_Whh = (const float*)d_in[10];
  const float* dec_bih = (const float*)d_in[11];
  const float* dec_bhh = (const float*)d_in[12];
  const float* W1 = (const float*)d_in[13];
  const float* b1 = (const float*)d_in[14];
  const float* W2 = (const float*)d_in[15];
  const float* b2 = (const float*)d_in[16];

  float* ws      = (float*)d_ws;
  float* enc_gx  = ws + OFF_ENC_GX;
  float* dec_gx  = ws + OFF_DEC_GX;
  float* enc_out = ws + OFF_ENC_OUT;
  float* hbuf    = ws + OFF_HBUF;
  float* Cmat    = ws + OFF_CMAT;
  float* OUT1    = ws + OFF_OUT1;
  unsigned* bar  = (unsigned*)(ws + OFF_BAR);

  // reset state every call (graph replays): barrier flags + h0 = 0
  hipMemsetAsync(bar, 0, SZ_BAR * sizeof(unsigned), stream);
  hipMemsetAsync(hbuf, 0, SZ_HBUF * sizeof(float), stream);

  dim3 blk(WGS);
  // gx precompute (gather-GEMMs)
  gemm_bt<0><<<dim3(G3_ / 64, (S_ * B_) / 64), blk, 0, stream>>>(
      enc_emb, method_code, enc_Wih, enc_bih, enc_gx, S_ * B_, G3_, DE_);
  gemm_bt<1><<<dim3(G3_ / 64, (TD_ * B_ + 63) / 64), blk, 0, stream>>>(
      dec_emb, method_summary, dec_Wih, dec_bih, dec_gx, TD_ * B_, G3_, DE_);

  // persistent GRU chains (encoder + decoder), 256 WGs
  recurrence_kernel<<<NWGR, blk, 0, stream>>>(enc_gx, dec_gx,
                                              enc_Whh, enc_bhh, dec_Whh, dec_bhh,
                                              enc_out, hbuf, Cmat, bar);

  // attention for all (td, b) in parallel
  attention_kernel<<<TD_ * B_, blk, 0, stream>>>(enc_out, Cmat);

  // output projection, batched over all 49*32 steps
  gemm_bt<2><<<dim3(H_ / 64, (TD_ * B_ + 63) / 64), blk, 0, stream>>>(
      Cmat, nullptr, W1, b1, OUT1, TD_ * B_, H_, 2 * H_);
  gemm_bt<3><<<dim3((VS_ + 63) / 64, (TD_ * B_ + 63) / 64), blk, 0, stream>>>(
      OUT1, nullptr, W2, b2, (float*)d_out, TD_ * B_, VS_, H_);
}

// Round 5
// 2600.021 us; speedup vs baseline: 5.9051x; 1.0662x over previous
//
#include <hip/hip_runtime.h>
#include <cmath>

#define WGS  256
#define NWGR 512         // recurrence workgroups (2 per CU)
#define DOMS 4           // independent batch domains
#define JGN  128         // j-groups (4 j each) per domain

typedef float    f32x4 __attribute__((ext_vector_type(4)));
typedef unsigned u32x2 __attribute__((ext_vector_type(2)));

// ---------------- sizes ----------------
#define B_   32
#define S_   200
#define L_   50
#define H_   512
#define DE_  256
#define VS_  30000
#define TD_  49          // L-1 decoder steps
#define G3_  1536        // 3*H

// ws layout (float offsets)
#define OFF_ENC_GX  ((size_t)0)                         // [200][32][1536]
#define SZ_ENC_GX   ((size_t)S_*B_*G3_)
#define OFF_DEC_GX  (OFF_ENC_GX + SZ_ENC_GX)            // [49][32][1536]
#define SZ_DEC_GX   ((size_t)TD_*B_*G3_)
#define OFF_ENC_OUT (OFF_DEC_GX + SZ_DEC_GX)            // [32][200][512]
#define SZ_ENC_OUT  ((size_t)B_*S_*H_)
#define OFF_HBUF    (OFF_ENC_OUT + SZ_ENC_OUT)          // [dom4][2][128][8][4]
#define SZ_HBUF     ((size_t)2*B_*H_)                   // 32768 floats
#define OFF_CMAT    (OFF_HBUF + SZ_HBUF)                // [49][32][1024]
#define SZ_CMAT     ((size_t)TD_*B_*2*H_)
#define OFF_OUT1    (OFF_CMAT + SZ_CMAT)                // [1568][512]
#define SZ_OUT1     ((size_t)TD_*B_*H_)
#define OFF_BAR     (OFF_OUT1 + SZ_OUT1)                // flags[dom][128]
#define SZ_BAR      ((size_t)(DOMS*JGN))                // uints

// LDS geometry (proven conflict-free in round 4): k-blocks of 64 @ stride 68
#define RSTR 548
#define KBLK 68

__device__ __forceinline__ f32x4 load_x4_cc(const f32x4* p) {
  f32x4 v;
  asm volatile("global_load_dwordx4 %0, %1, off sc0 sc1" : "=v"(v) : "v"(p) : "memory");
  return v;
}

// ---------------- persistent GRU-chain kernel ----------------
// 512 WGs: dom = w>>7 (8 batches each), jg = w&127 (4 j-values each).
// Compute thread: jl=t&3, bp=(t>>2)&3 (batch pair), kq=t>>4 (16 chunks of 32 k).
// Tail thread t<32: b=t>>2, jl=t&3.
__global__ __launch_bounds__(WGS, 2)
void recurrence_kernel(const float* __restrict__ enc_gx,
                       const float* __restrict__ dec_gx,
                       const float* __restrict__ eWhh, const float* __restrict__ eBhh,
                       const float* __restrict__ dWhh, const float* __restrict__ dBhh,
                       float* __restrict__ enc_out,
                       float* __restrict__ hbuf,
                       float* __restrict__ Cmat,
                       unsigned* __restrict__ barmem)
{
  __shared__ float wlds[12 * RSTR];   // 26304 B
  __shared__ float hlds[8 * RSTR];    // 17536 B
  __shared__ float red[384];          //  1536 B   (total 45376 B -> 2+/CU)

  const int t   = threadIdx.x;
  const int w   = blockIdx.x;
  const int dom = w >> 7;
  const int jg  = w & (JGN - 1);
  const int jl  = t & 3;
  const int bp  = (t >> 2) & 3;
  const int kq  = t >> 4;
  const int j   = (jg << 2) + jl;     // this WG's j for lanes t<32 (tail)
  const int bt_ = t >> 2;             // tail batch (t<32)
  const int b_g = (dom << 3) + bt_;   // global batch for tail

  unsigned* flags = barmem + dom * JGN;
  float* hdom = hbuf + (size_t)dom * 8192;   // [2][128][8][4]

  // stage Whh slice (12 rows x 512) into padded LDS layout
  auto stage_w = [&](const float* __restrict__ W) {
    for (int i = t; i < 12 * 128; i += WGS) {
      int row = i >> 7, kf = i & 127;
      int g = row >> 2, rl = row & 3;
      f32x4 v = *(const f32x4*)(W + ((size_t)(g * H_ + (jg << 2) + rl)) * H_ + (kf << 2));
      *(f32x4*)&wlds[row * RSTR + (kf >> 4) * KBLK + ((kf & 15) << 2)] = v;
    }
  };
  stage_w(eWhh);

  float bias_r = 0.f, bias_z = 0.f, bias_n = 0.f;
  if (t < 32) { bias_r = eBhh[j]; bias_z = eBhh[H_ + j]; bias_n = eBhh[2 * H_ + j]; }

  unsigned step = 0;
  int cur = 0;

  for (int s = 0; s < S_ + TD_; ++s) {
    const bool enc = (s < S_);
    if (s == S_) {   // switch to decoder weights (prev gbar synced the domain)
      stage_w(dWhh);
      if (t < 32) { bias_r = dBhh[j]; bias_z = dBhh[H_ + j]; bias_n = dBhh[2 * H_ + j]; }
    }

    // gx for the tail (cached loads, issued early to overlap staging)
    float gxr = 0.f, gxz = 0.f, gxn = 0.f;
    if (t < 32) {
      const float* gx = enc ? (enc_gx + ((size_t)s * B_ + b_g) * G3_)
                            : (dec_gx + ((size_t)(s - S_) * B_ + b_g) * G3_);
      gxr = gx[j]; gxz = gx[H_ + j]; gxn = gx[2 * H_ + j];
    }

    // ---- stage h[cur] (domain slab, 16 KB): 4 coalesced sc0sc1 loads ----
    {
      const f32x4* hsrc = (const f32x4*)(hdom + cur * 4096);
      f32x4 v0 = load_x4_cc(hsrc + t);
      f32x4 v1 = load_x4_cc(hsrc + 256 + t);
      f32x4 v2 = load_x4_cc(hsrc + 512 + t);
      f32x4 v3 = load_x4_cc(hsrc + 768 + t);
      asm volatile("s_waitcnt vmcnt(0)" ::: "memory");
      // unit u = i*256+t: jg' = u>>3, b = u&7 = t&7; dst k = 4*jg'
      #define HW(i, vv) { int q = (i * 256 + t) >> 3; \
        *(f32x4*)&hlds[(t & 7) * RSTR + ((q >> 4) * KBLK) + ((q & 15) << 2)] = vv; }
      HW(0, v0) HW(1, v1) HW(2, v2) HW(3, v3)
      #undef HW
    }
    __syncthreads();

    // ---- partial dots: 1 j x 3 gates x 2 batches x 32 k per thread ----
    {
      const int lofs = (kq >> 1) * KBLK + (kq & 1) * 32;
      const float* wr = &wlds[(0 + jl) * RSTR + lofs];
      const float* wz = &wlds[(4 + jl) * RSTR + lofs];
      const float* wn = &wlds[(8 + jl) * RSTR + lofs];
      const float* h0 = &hlds[(bp * 2 + 0) * RSTR + lofs];
      const float* h1 = &hlds[(bp * 2 + 1) * RSTR + lofs];
      float a0r = 0.f, a0z = 0.f, a0n = 0.f, a1r = 0.f, a1z = 0.f, a1n = 0.f;
      #pragma unroll
      for (int i = 0; i < 8; ++i) {
        f32x4 rv = *(const f32x4*)(wr + i * 4);
        f32x4 zv = *(const f32x4*)(wz + i * 4);
        f32x4 nv = *(const f32x4*)(wn + i * 4);
        f32x4 hv0 = *(const f32x4*)(h0 + i * 4);
        f32x4 hv1 = *(const f32x4*)(h1 + i * 4);
        a0r += hv0.x * rv.x + hv0.y * rv.y + hv0.z * rv.z + hv0.w * rv.w;
        a0z += hv0.x * zv.x + hv0.y * zv.y + hv0.z * zv.z + hv0.w * zv.w;
        a0n += hv0.x * nv.x + hv0.y * nv.y + hv0.z * nv.z + hv0.w * nv.w;
        a1r += hv1.x * rv.x + hv1.y * rv.y + hv1.z * rv.z + hv1.w * rv.w;
        a1z += hv1.x * zv.x + hv1.y * zv.y + hv1.z * zv.z + hv1.w * zv.w;
        a1n += hv1.x * nv.x + hv1.y * nv.y + hv1.z * nv.z + hv1.w * nv.w;
      }
      // fold kq within wave: t^16 (kq bit0), t^32 (kq bit1)
      a0r += __shfl_xor(a0r, 16); a0r += __shfl_xor(a0r, 32);
      a0z += __shfl_xor(a0z, 16); a0z += __shfl_xor(a0z, 32);
      a0n += __shfl_xor(a0n, 16); a0n += __shfl_xor(a0n, 32);
      a1r += __shfl_xor(a1r, 16); a1r += __shfl_xor(a1r, 32);
      a1z += __shfl_xor(a1z, 16); a1z += __shfl_xor(a1z, 32);
      a1n += __shfl_xor(a1n, 16); a1n += __shfl_xor(a1n, 32);
      if ((t & 48) == 0) {
        float* rd = &red[(t >> 6) * 96 + (t & 15) * 6];
        rd[0] = a0r; rd[1] = a0z; rd[2] = a0n; rd[3] = a1r; rd[4] = a1z; rd[5] = a1n;
      }
    }
    __syncthreads();

    // ---- tail: combine 4 wave-partials, gate math, state update ----
    if (t < 32) {
      const int idx = ((bt_ >> 1) * 4 + jl) * 6 + (bt_ & 1) * 3;
      float ar = red[idx] + red[96 + idx] + red[192 + idx] + red[288 + idx];
      float az = red[idx + 1] + red[96 + idx + 1] + red[192 + idx + 1] + red[288 + idx + 1];
      float an = red[idx + 2] + red[96 + idx + 2] + red[192 + idx + 2] + red[288 + idx + 2];
      float rg = 1.f / (1.f + expf(-(gxr + ar + bias_r)));
      float zg = 1.f / (1.f + expf(-(gxz + az + bias_z)));
      float ng = tanhf(gxn + rg * (an + bias_n));
      float hprev = hlds[bt_ * RSTR + (j >> 6) * KBLK + (j & 63)];
      float hn = (1.f - zg) * ng + zg * hprev;
      // producer block: 32 consecutive dwords = 2 cachelines (fast ack)
      __hip_atomic_store(hdom + (cur ^ 1) * 4096 + (jg << 5) + t, hn,
                         __ATOMIC_RELAXED, __HIP_MEMORY_SCOPE_AGENT);
      if (enc) enc_out[((size_t)b_g * S_ + s) * H_ + j] = hn;
      else     Cmat[((size_t)(s - S_) * B_ + b_g) * (2 * H_) + H_ + j] = hn;
    }
    cur ^= 1;

    // ---- domain barrier (128 flags) ----
    if (s < S_ + TD_ - 1) {
      ++step;
      __syncthreads();                    // red/hlds safe; wave0 h-stores in program order below
      if (t == 0) {
        asm volatile("s_waitcnt vmcnt(0)" ::: "memory");   // h-store (wave0) acked at L3
        const unsigned* fp = flags + jg;
        asm volatile("global_store_dword %0, %1, off sc0 sc1"
                     :: "v"(fp), "v"(step) : "memory");
      }
      if (t < 64) {   // wave 0 polls: 2 flags/lane covers all 128
        const unsigned* base = flags + (t << 1);
        while (true) {
          u32x2 v;
          asm volatile("global_load_dwordx2 %0, %1, off sc0 sc1"
                       : "=v"(v) : "v"(base) : "memory");
          asm volatile("s_waitcnt vmcnt(0)" ::: "memory");
          unsigned mn = min((unsigned)v.x, (unsigned)v.y);
          if (__all(mn >= step)) break;
          __builtin_amdgcn_s_sleep(1);
        }
      }
      __syncthreads();
    }
  }
}

// ---------------- attention kernel: one WG per (td, b) ----------------
__global__ __launch_bounds__(WGS)
void attention_kernel(const float* __restrict__ enc_out,
                      float* __restrict__ Cmat)
{
  const int task = blockIdx.x;          // td*32 + b
  const int td = task >> 5, b = task & 31;
  const int t = threadIdx.x;
  const float* h = Cmat + ((size_t)td * B_ + b) * (2 * H_) + H_;

  __shared__ float red[WGS];
  __shared__ float p[WGS];              // 200 used

  float sv = -1e30f;
  if (t < S_) {
    const float* eo = enc_out + ((size_t)b * S_ + t) * H_;
    float acc = 0.f;
    #pragma unroll 4
    for (int k = 0; k < H_; k += 4) {
      float4 e = *(const float4*)(eo + k);
      float4 hv = *(const float4*)(h + k);
      acc += e.x * hv.x + e.y * hv.y + e.z * hv.z + e.w * hv.w;
    }
    sv = acc;
  }
  red[t] = sv; __syncthreads();
  for (int o = 128; o; o >>= 1) { if (t < o) red[t] = fmaxf(red[t], red[t + o]); __syncthreads(); }
  float mx = red[0]; __syncthreads();
  float ev = (t < S_) ? expf(sv - mx) : 0.f;
  red[t] = ev; __syncthreads();
  for (int o = 128; o; o >>= 1) { if (t < o) red[t] += red[t + o]; __syncthreads(); }
  float inv = 1.f / red[0];
  p[t] = ev * inv;
  __syncthreads();

  const float* eo = enc_out + (size_t)b * S_ * H_ + (t << 1);
  float ax = 0.f, ay = 0.f;
  for (int i = 0; i < S_; ++i) {
    float pi = p[i];
    float2 v = *(const float2*)(eo + (size_t)i * H_);
    ax += pi * v.x; ay += pi * v.y;
  }
  float* cd = Cmat + ((size_t)td * B_ + b) * (2 * H_) + (t << 1);
  cd[0] = ax; cd[1] = ay;
}

// ---------------- tiled fp32 GEMM 64x64 (modes 0/1/2) ----------------
template<int MODE>
__launch_bounds__(WGS)
__global__ void gemm_bt(const float* __restrict__ A,
                        const int* __restrict__ idx,
                        const float* __restrict__ Bw,
                        const float* __restrict__ bias,
                        float* __restrict__ Cdst,
                        int M, int N, int K)
{
  const int BM = 64, BN = 64, BK = 16;
  __shared__ float As[BK][BM];
  __shared__ float Bs[BK][BN];
  __shared__ int toks[BM];
  const int m0 = blockIdx.y * BM, n0 = blockIdx.x * BN;
  const int t = threadIdx.x;
  const int tx = t & 15, ty = t >> 4;
  float acc[4][4] = {{0.f}};

  if (MODE <= 1) {
    if (t < BM) {
      int m = m0 + t;
      int tok = 0;
      if (m < M) {
        int bidx = m & 31, srow = m >> 5;
        tok = (MODE == 0) ? idx[bidx * S_ + srow] : idx[bidx * L_ + srow];
      }
      toks[t] = tok;
    }
    __syncthreads();
  }

  const int row = t >> 2, kk = (t & 3) * 4;
  for (int k0 = 0; k0 < K; k0 += BK) {
    {
      int m = m0 + row;
      float4 v = {0.f, 0.f, 0.f, 0.f};
      if (m < M) {
        const float* src = (MODE <= 1) ? (A + (size_t)toks[row] * K + k0 + kk)
                                       : (A + (size_t)m * K + k0 + kk);
        v = *(const float4*)src;
      }
      As[kk][row] = v.x; As[kk + 1][row] = v.y; As[kk + 2][row] = v.z; As[kk + 3][row] = v.w;
      int n = n0 + row;
      float4 wv = {0.f, 0.f, 0.f, 0.f};
      if (n < N) wv = *(const float4*)(Bw + (size_t)n * K + k0 + kk);
      Bs[kk][row] = wv.x; Bs[kk + 1][row] = wv.y; Bs[kk + 2][row] = wv.z; Bs[kk + 3][row] = wv.w;
    }
    __syncthreads();
    #pragma unroll
    for (int k = 0; k < BK; ++k) {
      float a[4], bq[4];
      *(float4*)a  = *(const float4*)&As[k][ty * 4];
      *(float4*)bq = *(const float4*)&Bs[k][tx * 4];
      #pragma unroll
      for (int i = 0; i < 4; ++i)
        #pragma unroll
        for (int jj = 0; jj < 4; ++jj)
          acc[i][jj] += a[i] * bq[jj];
    }
    __syncthreads();
  }

  #pragma unroll
  for (int i = 0; i < 4; ++i) {
    int m = m0 + ty * 4 + i;
    if (m >= M) continue;
    #pragma unroll
    for (int jj = 0; jj < 4; ++jj) {
      int n = n0 + tx * 4 + jj;
      if (n >= N) continue;
      float v = acc[i][jj] + bias[n];
      if (MODE == 2) v = fmaxf(v, 0.f);
      Cdst[(size_t)m * N + n] = v;
    }
  }
}

// ---------------- 128x128 fp32 GEMM for the vocab projection ----------------
// out[b][td][n] = OUT1[m] @ W2[n] + b2[n],  m = td*32+b  (M=1568, N=30000, K=512)
__global__ __launch_bounds__(WGS)
void gemm128_out(const float* __restrict__ A,   // [M][512]
                 const float* __restrict__ Bw,  // [N][512]
                 const float* __restrict__ bias,
                 float* __restrict__ out)
{
  const int APAD = 132;
  __shared__ float As[16 * APAD];
  __shared__ float Bs[16 * APAD];
  const int n0 = blockIdx.x * 128, m0 = blockIdx.y * 128;
  const int t = threadIdx.x;
  const int tx = t & 15, ty = t >> 4;
  const int M = TD_ * B_, N = VS_, K = H_;

  float acc[8][8];
  #pragma unroll
  for (int i = 0; i < 8; ++i)
    #pragma unroll
    for (int jj = 0; jj < 8; ++jj) acc[i][jj] = 0.f;

  const int srow = t >> 2, skk = (t & 3) * 4;
  for (int k0 = 0; k0 < K; k0 += 16) {
    #pragma unroll
    for (int u = 0; u < 2; ++u) {
      int row = srow + u * 64;
      int m = m0 + row;
      f32x4 av = {0.f, 0.f, 0.f, 0.f};
      if (m < M) av = *(const f32x4*)(A + (size_t)m * K + k0 + skk);
      As[(skk + 0) * APAD + row] = av.x;
      As[(skk + 1) * APAD + row] = av.y;
      As[(skk + 2) * APAD + row] = av.z;
      As[(skk + 3) * APAD + row] = av.w;
      int n = n0 + row;
      f32x4 bv = {0.f, 0.f, 0.f, 0.f};
      if (n < N) bv = *(const f32x4*)(Bw + (size_t)n * K + k0 + skk);
      Bs[(skk + 0) * APAD + row] = bv.x;
      Bs[(skk + 1) * APAD + row] = bv.y;
      Bs[(skk + 2) * APAD + row] = bv.z;
      Bs[(skk + 3) * APAD + row] = bv.w;
    }
    __syncthreads();
    #pragma unroll
    for (int k = 0; k < 16; ++k) {
      f32x4 a0 = *(const f32x4*)&As[k * APAD + ty * 8];
      f32x4 a1 = *(const f32x4*)&As[k * APAD + ty * 8 + 4];
      f32x4 b0 = *(const f32x4*)&Bs[k * APAD + tx * 4];
      f32x4 b1 = *(const f32x4*)&Bs[k * APAD + 64 + tx * 4];
      float a[8] = {a0.x, a0.y, a0.z, a0.w, a1.x, a1.y, a1.z, a1.w};
      float bb[8] = {b0.x, b0.y, b0.z, b0.w, b1.x, b1.y, b1.z, b1.w};
      #pragma unroll
      for (int i = 0; i < 8; ++i)
        #pragma unroll
        for (int jj = 0; jj < 8; ++jj)
          acc[i][jj] += a[i] * bb[jj];
    }
    __syncthreads();
  }

  const bool edge = (n0 + 128 > N);
  f32x4 bias0 = {0,0,0,0}, bias1 = {0,0,0,0};
  if (!edge) {
    bias0 = *(const f32x4*)(bias + n0 + tx * 4);
    bias1 = *(const f32x4*)(bias + n0 + 64 + tx * 4);
  }
  #pragma unroll
  for (int i = 0; i < 8; ++i) {
    int m = m0 + ty * 8 + i;
    if (m >= M) continue;
    int bidx = m & 31, td = m >> 5;
    float* orow = out + ((size_t)bidx * TD_ + td) * (size_t)VS_;
    if (!edge) {
      f32x4 v0 = { acc[i][0] + bias0.x, acc[i][1] + bias0.y,
                   acc[i][2] + bias0.z, acc[i][3] + bias0.w };
      f32x4 v1 = { acc[i][4] + bias1.x, acc[i][5] + bias1.y,
                   acc[i][6] + bias1.z, acc[i][7] + bias1.w };
      *(f32x4*)(orow + n0 + tx * 4) = v0;
      *(f32x4*)(orow + n0 + 64 + tx * 4) = v1;
    } else {
      #pragma unroll
      for (int jj = 0; jj < 8; ++jj) {
        int n = n0 + (jj >> 2) * 64 + tx * 4 + (jj & 3);
        if (n < N) orow[n] = acc[i][jj] + bias[n];
      }
    }
  }
}

// ---------------- launch ----------------
extern "C" void kernel_launch(void* const* d_in, const int* in_sizes, int n_in,
                              void* d_out, int out_size, void* d_ws, size_t ws_size,
                              hipStream_t stream) {
  const int*   method_code    = (const int*)d_in[0];
  const int*   method_summary = (const int*)d_in[1];
  const float* enc_emb = (const float*)d_in[3];
  const float* enc_Wih = (const float*)d_in[4];
  const float* enc_Whh = (const float*)d_in[5];
  const float* enc_bih = (const float*)d_in[6];
  const float* enc_bhh = (const float*)d_in[7];
  const float* dec_emb = (const float*)d_in[8];
  const float* dec_Wih = (const float*)d_in[9];
  const float* dec_Whh = (const float*)d_in[10];
  const float* dec_bih = (const float*)d_in[11];
  const float* dec_bhh = (const float*)d_in[12];
  const float* W1 = (const float*)d_in[13];
  const float* b1 = (const float*)d_in[14];
  const float* W2 = (const float*)d_in[15];
  const float* b2 = (const float*)d_in[16];

  float* ws      = (float*)d_ws;
  float* enc_gx  = ws + OFF_ENC_GX;
  float* dec_gx  = ws + OFF_DEC_GX;
  float* enc_out = ws + OFF_ENC_OUT;
  float* hbuf    = ws + OFF_HBUF;
  float* Cmat    = ws + OFF_CMAT;
  float* OUT1    = ws + OFF_OUT1;
  unsigned* bar  = (unsigned*)(ws + OFF_BAR);

  // reset state every call (graph replays): barrier flags + h0 = 0
  hipMemsetAsync(bar, 0, SZ_BAR * sizeof(unsigned), stream);
  hipMemsetAsync(hbuf, 0, SZ_HBUF * sizeof(float), stream);

  dim3 blk(WGS);
  // gx precompute (gather-GEMMs)
  gemm_bt<0><<<dim3(G3_ / 64, (S_ * B_) / 64), blk, 0, stream>>>(
      enc_emb, method_code, enc_Wih, enc_bih, enc_gx, S_ * B_, G3_, DE_);
  gemm_bt<1><<<dim3(G3_ / 64, (TD_ * B_ + 63) / 64), blk, 0, stream>>>(
      dec_emb, method_summary, dec_Wih, dec_bih, dec_gx, TD_ * B_, G3_, DE_);

  // persistent GRU chains: 512 WGs, 4 independent domains
  recurrence_kernel<<<NWGR, blk, 0, stream>>>(enc_gx, dec_gx,
                                              enc_Whh, enc_bhh, dec_Whh, dec_bhh,
                                              enc_out, hbuf, Cmat, bar);

  // attention for all (td, b) in parallel
  attention_kernel<<<TD_ * B_, blk, 0, stream>>>(enc_out, Cmat);

  // output projection
  gemm_bt<2><<<dim3(H_ / 64, (TD_ * B_ + 63) / 64), blk, 0, stream>>>(
      Cmat, nullptr, W1, b1, OUT1, TD_ * B_, H_, 2 * H_);
  gemm128_out<<<dim3((VS_ + 127) / 128, (TD_ * B_ + 127) / 128), blk, 0, stream>>>(
      OUT1, W2, b2, (float*)d_out);
}

// Round 6
// 2081.898 us; speedup vs baseline: 7.3746x; 1.2489x over previous
//
#include <hip/hip_runtime.h>
#include <cmath>

#define WGS  256
#define NWGR 512         // recurrence workgroups (2 per CU)
#define DOMS 4           // independent batch domains
#define JGN  128         // j-groups (4 j each) per domain
#define HBDW 6144        // dwords per h exchange buffer per domain (128 blocks x 48)

typedef float    f32x4 __attribute__((ext_vector_type(4)));
typedef unsigned u32x4 __attribute__((ext_vector_type(4)));

// ---------------- sizes ----------------
#define B_   32
#define S_   200
#define L_   50
#define H_   512
#define DE_  256
#define VS_  30000
#define TD_  49          // L-1 decoder steps
#define G3_  1536        // 3*H

// ws layout (float offsets)
#define OFF_ENC_GX  ((size_t)0)                         // [200][32][1536]
#define SZ_ENC_GX   ((size_t)S_*B_*G3_)
#define OFF_DEC_GX  (OFF_ENC_GX + SZ_ENC_GX)            // [49][32][1536]
#define SZ_DEC_GX   ((size_t)TD_*B_*G3_)
#define OFF_ENC_OUT (OFF_DEC_GX + SZ_DEC_GX)            // [32][200][512]
#define SZ_ENC_OUT  ((size_t)B_*S_*H_)
#define OFF_HBUF    (OFF_ENC_OUT + SZ_ENC_OUT)          // [dom4][buf2][6144] tagged
#define SZ_HBUF     ((size_t)DOMS*2*HBDW)               // 49152 floats
#define OFF_CMAT    (OFF_HBUF + SZ_HBUF)                // [49][32][1024]
#define SZ_CMAT     ((size_t)TD_*B_*2*H_)
#define OFF_OUT1    (OFF_CMAT + SZ_CMAT)                // [1568][512]
#define SZ_OUT1     ((size_t)TD_*B_*H_)

// LDS geometry (proven conflict-free): k-blocks of 64 @ stride 68
#define RSTR 548
#define KBLK 68

__device__ __forceinline__ u32x4 load_u4_cc(const unsigned* p) {
  u32x4 v;
  asm volatile("global_load_dwordx4 %0, %1, off sc0 sc1" : "=v"(v) : "v"(p) : "memory");
  return v;
}

// ---------------- persistent GRU-chain kernel, barrier-free ----------------
// 512 WGs: dom = w>>7 (8 batches each), jg = w&127 (4 j-values each).
// h exchange: per domain/parity, 128 blocks of 48 dwords (3 cachelines);
// each 64B line = [tag, 15 payloads]; payload index p (=b*4+jl, p<32) sits at
// block dword pos with p = pos - 1 - pos/16 (pos in 1..34). Tag s+1 rides in
// the same line as its h_{s+1} payload -> consumers poll the data itself.
__global__ __launch_bounds__(WGS, 2)
void recurrence_kernel(const float* __restrict__ enc_gx,
                       const float* __restrict__ dec_gx,
                       const float* __restrict__ eWhh, const float* __restrict__ eBhh,
                       const float* __restrict__ dWhh, const float* __restrict__ dBhh,
                       float* __restrict__ enc_out,
                       float* __restrict__ hbuf,
                       float* __restrict__ Cmat)
{
  __shared__ float wlds[12 * RSTR];   // 26304 B
  __shared__ float hlds[8 * RSTR];    // 17536 B
  __shared__ float red[384];          //  1536 B

  const int t   = threadIdx.x;
  const int w   = blockIdx.x;
  const int dom = w >> 7;
  const int jg  = w & (JGN - 1);
  const int jl  = t & 3;
  const int bp  = (t >> 2) & 3;
  const int kq  = t >> 4;
  const int j   = (jg << 2) + jl;     // tail j (t<32)
  const int bt_ = t >> 2;             // tail batch (t<32)
  const int b_g = (dom << 3) + bt_;

  float* hdom = hbuf + (size_t)dom * (2 * HBDW);

  // per-thread staging constants: 6 dwordx4 loads at dword offset i*1024+4t
  int rr[6], lb[6];
  #pragma unroll
  for (int i = 0; i < 6; ++i) {
    int g = i * 1024 + (t << 2);
    int blk = g / 48;
    rr[i] = g - blk * 48;
    lb[i] = (blk >> 4) * KBLK + ((blk & 15) << 2);
  }

  auto stage_w = [&](const float* __restrict__ W) {
    for (int i = t; i < 12 * 128; i += WGS) {
      int row = i >> 7, kf = i & 127;
      int g = row >> 2, rl = row & 3;
      f32x4 v = *(const f32x4*)(W + ((size_t)(g * H_ + (jg << 2) + rl)) * H_ + (kf << 2));
      *(f32x4*)&wlds[row * RSTR + (kf >> 4) * KBLK + ((kf & 15) << 2)] = v;
    }
  };
  stage_w(eWhh);

  float bias_r = 0.f, bias_z = 0.f, bias_n = 0.f;
  if (t < 32) { bias_r = eBhh[j]; bias_z = eBhh[H_ + j]; bias_n = eBhh[2 * H_ + j]; }

  for (int s = 0; s < S_ + TD_; ++s) {
    const bool enc = (s < S_);
    __syncthreads();    // prev step's compute/tail done; hlds/red/wlds reusable
    if (s == S_) {      // switch to decoder weights
      stage_w(dWhh);
      if (t < 32) { bias_r = dBhh[j]; bias_z = dBhh[H_ + j]; bias_n = dBhh[2 * H_ + j]; }
    }

    // gx for the tail (cached loads, issued early)
    float gxr = 0.f, gxz = 0.f, gxn = 0.f;
    if (t < 32) {
      const float* gx = enc ? (enc_gx + ((size_t)s * B_ + b_g) * G3_)
                            : (dec_gx + ((size_t)(s - S_) * B_ + b_g) * G3_);
      gxr = gx[j]; gxz = gx[H_ + j]; gxn = gx[2 * H_ + j];
    }

    // ---- stage h_s: poll tagged lines until fresh, scatter to LDS ----
    {
      const unsigned* hb = (const unsigned*)(hdom + (size_t)(s & 1) * HBDW);
      const unsigned tagreq = (unsigned)s;
      u32x4 v0, v1, v2, v3, v4, v5;
      while (true) {
        v0 = load_u4_cc(hb + 0 * 1024 + (t << 2));
        v1 = load_u4_cc(hb + 1 * 1024 + (t << 2));
        v2 = load_u4_cc(hb + 2 * 1024 + (t << 2));
        v3 = load_u4_cc(hb + 3 * 1024 + (t << 2));
        v4 = load_u4_cc(hb + 4 * 1024 + (t << 2));
        v5 = load_u4_cc(hb + 5 * 1024 + (t << 2));
        asm volatile("s_waitcnt vmcnt(0)" ::: "memory");
        bool ok = true;
        if ((rr[0] & 15) == 0) ok &= ((unsigned)v0.x >= tagreq);
        if ((rr[1] & 15) == 0) ok &= ((unsigned)v1.x >= tagreq);
        if ((rr[2] & 15) == 0) ok &= ((unsigned)v2.x >= tagreq);
        if ((rr[3] & 15) == 0) ok &= ((unsigned)v3.x >= tagreq);
        if ((rr[4] & 15) == 0) ok &= ((unsigned)v4.x >= tagreq);
        if ((rr[5] & 15) == 0) ok &= ((unsigned)v5.x >= tagreq);
        if (__all(ok)) break;
        __builtin_amdgcn_s_sleep(1);
      }
      #define SCAT(vv, ii) { \
        _Pragma("unroll") \
        for (int d = 0; d < 4; ++d) { \
          int pos = rr[ii] + d; \
          if ((pos & 15) != 0 && pos < 35) { \
            int p = pos - 1 - (pos >> 4); \
            hlds[(p >> 2) * RSTR + lb[ii] + (p & 3)] = __uint_as_float(vv[d]); \
          } } }
      SCAT(v0, 0) SCAT(v1, 1) SCAT(v2, 2) SCAT(v3, 3) SCAT(v4, 4) SCAT(v5, 5)
      #undef SCAT
    }
    __syncthreads();

    // ---- partial dots: 1 j x 3 gates x 2 batches x 32 k per thread ----
    {
      const int lofs = (kq >> 1) * KBLK + (kq & 1) * 32;
      const float* wr = &wlds[(0 + jl) * RSTR + lofs];
      const float* wz = &wlds[(4 + jl) * RSTR + lofs];
      const float* wn = &wlds[(8 + jl) * RSTR + lofs];
      const float* h0 = &hlds[(bp * 2 + 0) * RSTR + lofs];
      const float* h1 = &hlds[(bp * 2 + 1) * RSTR + lofs];
      float a0r = 0.f, a0z = 0.f, a0n = 0.f, a1r = 0.f, a1z = 0.f, a1n = 0.f;
      #pragma unroll
      for (int i = 0; i < 8; ++i) {
        f32x4 rv = *(const f32x4*)(wr + i * 4);
        f32x4 zv = *(const f32x4*)(wz + i * 4);
        f32x4 nv = *(const f32x4*)(wn + i * 4);
        f32x4 hv0 = *(const f32x4*)(h0 + i * 4);
        f32x4 hv1 = *(const f32x4*)(h1 + i * 4);
        a0r += hv0.x * rv.x + hv0.y * rv.y + hv0.z * rv.z + hv0.w * rv.w;
        a0z += hv0.x * zv.x + hv0.y * zv.y + hv0.z * zv.z + hv0.w * zv.w;
        a0n += hv0.x * nv.x + hv0.y * nv.y + hv0.z * nv.z + hv0.w * nv.w;
        a1r += hv1.x * rv.x + hv1.y * rv.y + hv1.z * rv.z + hv1.w * rv.w;
        a1z += hv1.x * zv.x + hv1.y * zv.y + hv1.z * zv.z + hv1.w * zv.w;
        a1n += hv1.x * nv.x + hv1.y * nv.y + hv1.z * nv.z + hv1.w * nv.w;
      }
      a0r += __shfl_xor(a0r, 16); a0r += __shfl_xor(a0r, 32);
      a0z += __shfl_xor(a0z, 16); a0z += __shfl_xor(a0z, 32);
      a0n += __shfl_xor(a0n, 16); a0n += __shfl_xor(a0n, 32);
      a1r += __shfl_xor(a1r, 16); a1r += __shfl_xor(a1r, 32);
      a1z += __shfl_xor(a1z, 16); a1z += __shfl_xor(a1z, 32);
      a1n += __shfl_xor(a1n, 16); a1n += __shfl_xor(a1n, 32);
      if ((t & 48) == 0) {
        float* rd = &red[(t >> 6) * 96 + (t & 15) * 6];
        rd[0] = a0r; rd[1] = a0z; rd[2] = a0n; rd[3] = a1r; rd[4] = a1z; rd[5] = a1n;
      }
    }
    __syncthreads();

    // ---- tail: combine wave-partials, gate math, tagged h publish ----
    float hn = 0.f;
    if (t < 32) {
      const int idx = ((bt_ >> 1) * 4 + jl) * 6 + (bt_ & 1) * 3;
      float ar = red[idx] + red[96 + idx] + red[192 + idx] + red[288 + idx];
      float az = red[idx + 1] + red[96 + idx + 1] + red[192 + idx + 1] + red[288 + idx + 1];
      float an = red[idx + 2] + red[96 + idx + 2] + red[192 + idx + 2] + red[288 + idx + 2];
      float rg = 1.f / (1.f + expf(-(gxr + ar + bias_r)));
      float zg = 1.f / (1.f + expf(-(gxz + az + bias_z)));
      float ng = tanhf(gxn + rg * (an + bias_n));
      float hprev = hlds[bt_ * RSTR + (j >> 6) * KBLK + (j & 63)];
      hn = (1.f - zg) * ng + zg * hprev;
      if (enc) enc_out[((size_t)b_g * S_ + s) * H_ + j] = hn;
      else     Cmat[((size_t)(s - S_) * B_ + b_g) * (2 * H_) + H_ + j] = hn;
    }
    // publish h_{s+1}: one tagged fire-and-forget store, lanes 0..34
    {
      unsigned* pb = (unsigned*)(hdom + (size_t)((s + 1) & 1) * HBDW) + jg * 48;
      if (t < 35) {
        int src = t - ((t < 16) ? 1 : ((t < 32) ? 2 : 3));
        src = src < 0 ? 0 : src;
        float pv = __shfl(hn, src);
        unsigned val = ((t & 15) == 0) ? (unsigned)(s + 1) : __float_as_uint(pv);
        __hip_atomic_store(pb + t, val, __ATOMIC_RELAXED, __HIP_MEMORY_SCOPE_AGENT);
      }
    }
  }
}

// ---------------- attention kernel: one WG per (td, b) ----------------
__global__ __launch_bounds__(WGS)
void attention_kernel(const float* __restrict__ enc_out,
                      float* __restrict__ Cmat)
{
  const int task = blockIdx.x;          // td*32 + b
  const int td = task >> 5, b = task & 31;
  const int t = threadIdx.x;
  const float* h = Cmat + ((size_t)td * B_ + b) * (2 * H_) + H_;

  __shared__ float red[WGS];
  __shared__ float p[WGS];              // 200 used

  float sv = -1e30f;
  if (t < S_) {
    const float* eo = enc_out + ((size_t)b * S_ + t) * H_;
    float acc = 0.f;
    #pragma unroll 4
    for (int k = 0; k < H_; k += 4) {
      float4 e = *(const float4*)(eo + k);
      float4 hv = *(const float4*)(h + k);
      acc += e.x * hv.x + e.y * hv.y + e.z * hv.z + e.w * hv.w;
    }
    sv = acc;
  }
  red[t] = sv; __syncthreads();
  for (int o = 128; o; o >>= 1) { if (t < o) red[t] = fmaxf(red[t], red[t + o]); __syncthreads(); }
  float mx = red[0]; __syncthreads();
  float ev = (t < S_) ? expf(sv - mx) : 0.f;
  red[t] = ev; __syncthreads();
  for (int o = 128; o; o >>= 1) { if (t < o) red[t] += red[t + o]; __syncthreads(); }
  float inv = 1.f / red[0];
  p[t] = ev * inv;
  __syncthreads();

  const float* eo = enc_out + (size_t)b * S_ * H_ + (t << 1);
  float ax = 0.f, ay = 0.f;
  for (int i = 0; i < S_; ++i) {
    float pi = p[i];
    float2 v = *(const float2*)(eo + (size_t)i * H_);
    ax += pi * v.x; ay += pi * v.y;
  }
  float* cd = Cmat + ((size_t)td * B_ + b) * (2 * H_) + (t << 1);
  cd[0] = ax; cd[1] = ay;
}

// ---------------- tiled fp32 GEMM 64x64 (modes 0/1/2) ----------------
template<int MODE>
__launch_bounds__(WGS)
__global__ void gemm_bt(const float* __restrict__ A,
                        const int* __restrict__ idx,
                        const float* __restrict__ Bw,
                        const float* __restrict__ bias,
                        float* __restrict__ Cdst,
                        int M, int N, int K)
{
  const int BM = 64, BN = 64, BK = 16;
  __shared__ float As[BK][BM];
  __shared__ float Bs[BK][BN];
  __shared__ int toks[BM];
  const int m0 = blockIdx.y * BM, n0 = blockIdx.x * BN;
  const int t = threadIdx.x;
  const int tx = t & 15, ty = t >> 4;
  float acc[4][4] = {{0.f}};

  if (MODE <= 1) {
    if (t < BM) {
      int m = m0 + t;
      int tok = 0;
      if (m < M) {
        int bidx = m & 31, srow = m >> 5;
        tok = (MODE == 0) ? idx[bidx * S_ + srow] : idx[bidx * L_ + srow];
      }
      toks[t] = tok;
    }
    __syncthreads();
  }

  const int row = t >> 2, kk = (t & 3) * 4;
  for (int k0 = 0; k0 < K; k0 += BK) {
    {
      int m = m0 + row;
      float4 v = {0.f, 0.f, 0.f, 0.f};
      if (m < M) {
        const float* src = (MODE <= 1) ? (A + (size_t)toks[row] * K + k0 + kk)
                                       : (A + (size_t)m * K + k0 + kk);
        v = *(const float4*)src;
      }
      As[kk][row] = v.x; As[kk + 1][row] = v.y; As[kk + 2][row] = v.z; As[kk + 3][row] = v.w;
      int n = n0 + row;
      float4 wv = {0.f, 0.f, 0.f, 0.f};
      if (n < N) wv = *(const float4*)(Bw + (size_t)n * K + k0 + kk);
      Bs[kk][row] = wv.x; Bs[kk + 1][row] = wv.y; Bs[kk + 2][row] = wv.z; Bs[kk + 3][row] = wv.w;
    }
    __syncthreads();
    #pragma unroll
    for (int k = 0; k < BK; ++k) {
      float a[4], bq[4];
      *(float4*)a  = *(const float4*)&As[k][ty * 4];
      *(float4*)bq = *(const float4*)&Bs[k][tx * 4];
      #pragma unroll
      for (int i = 0; i < 4; ++i)
        #pragma unroll
        for (int jj = 0; jj < 4; ++jj)
          acc[i][jj] += a[i] * bq[jj];
    }
    __syncthreads();
  }

  #pragma unroll
  for (int i = 0; i < 4; ++i) {
    int m = m0 + ty * 4 + i;
    if (m >= M) continue;
    #pragma unroll
    for (int jj = 0; jj < 4; ++jj) {
      int n = n0 + tx * 4 + jj;
      if (n >= N) continue;
      float v = acc[i][jj] + bias[n];
      if (MODE == 2) v = fmaxf(v, 0.f);
      Cdst[(size_t)m * N + n] = v;
    }
  }
}

// ---------------- 128x128 fp32 GEMM for the vocab projection ----------------
__global__ __launch_bounds__(WGS)
void gemm128_out(const float* __restrict__ A,   // [M][512]
                 const float* __restrict__ Bw,  // [N][512]
                 const float* __restrict__ bias,
                 float* __restrict__ out)
{
  const int APAD = 132;
  __shared__ float As[16 * APAD];
  __shared__ float Bs[16 * APAD];
  const int n0 = blockIdx.x * 128, m0 = blockIdx.y * 128;
  const int t = threadIdx.x;
  const int tx = t & 15, ty = t >> 4;
  const int M = TD_ * B_, N = VS_, K = H_;

  float acc[8][8];
  #pragma unroll
  for (int i = 0; i < 8; ++i)
    #pragma unroll
    for (int jj = 0; jj < 8; ++jj) acc[i][jj] = 0.f;

  const int srow = t >> 2, skk = (t & 3) * 4;
  for (int k0 = 0; k0 < K; k0 += 16) {
    #pragma unroll
    for (int u = 0; u < 2; ++u) {
      int row = srow + u * 64;
      int m = m0 + row;
      f32x4 av = {0.f, 0.f, 0.f, 0.f};
      if (m < M) av = *(const f32x4*)(A + (size_t)m * K + k0 + skk);
      As[(skk + 0) * APAD + row] = av.x;
      As[(skk + 1) * APAD + row] = av.y;
      As[(skk + 2) * APAD + row] = av.z;
      As[(skk + 3) * APAD + row] = av.w;
      int n = n0 + row;
      f32x4 bv = {0.f, 0.f, 0.f, 0.f};
      if (n < N) bv = *(const f32x4*)(Bw + (size_t)n * K + k0 + skk);
      Bs[(skk + 0) * APAD + row] = bv.x;
      Bs[(skk + 1) * APAD + row] = bv.y;
      Bs[(skk + 2) * APAD + row] = bv.z;
      Bs[(skk + 3) * APAD + row] = bv.w;
    }
    __syncthreads();
    #pragma unroll
    for (int k = 0; k < 16; ++k) {
      f32x4 a0 = *(const f32x4*)&As[k * APAD + ty * 8];
      f32x4 a1 = *(const f32x4*)&As[k * APAD + ty * 8 + 4];
      f32x4 b0 = *(const f32x4*)&Bs[k * APAD + tx * 4];
      f32x4 b1 = *(const f32x4*)&Bs[k * APAD + 64 + tx * 4];
      float a[8] = {a0.x, a0.y, a0.z, a0.w, a1.x, a1.y, a1.z, a1.w};
      float bb[8] = {b0.x, b0.y, b0.z, b0.w, b1.x, b1.y, b1.z, b1.w};
      #pragma unroll
      for (int i = 0; i < 8; ++i)
        #pragma unroll
        for (int jj = 0; jj < 8; ++jj)
          acc[i][jj] += a[i] * bb[jj];
    }
    __syncthreads();
  }

  const bool edge = (n0 + 128 > N);
  f32x4 bias0 = {0,0,0,0}, bias1 = {0,0,0,0};
  if (!edge) {
    bias0 = *(const f32x4*)(bias + n0 + tx * 4);
    bias1 = *(const f32x4*)(bias + n0 + 64 + tx * 4);
  }
  #pragma unroll
  for (int i = 0; i < 8; ++i) {
    int m = m0 + ty * 8 + i;
    if (m >= M) continue;
    int bidx = m & 31, td = m >> 5;
    float* orow = out + ((size_t)bidx * TD_ + td) * (size_t)VS_;
    if (!edge) {
      f32x4 v0 = { acc[i][0] + bias0.x, acc[i][1] + bias0.y,
                   acc[i][2] + bias0.z, acc[i][3] + bias0.w };
      f32x4 v1 = { acc[i][4] + bias1.x, acc[i][5] + bias1.y,
                   acc[i][6] + bias1.z, acc[i][7] + bias1.w };
      *(f32x4*)(orow + n0 + tx * 4) = v0;
      *(f32x4*)(orow + n0 + 64 + tx * 4) = v1;
    } else {
      #pragma unroll
      for (int jj = 0; jj < 8; ++jj) {
        int n = n0 + (jj >> 2) * 64 + tx * 4 + (jj & 3);
        if (n < N) orow[n] = acc[i][jj] + bias[n];
      }
    }
  }
}

// ---------------- launch ----------------
extern "C" void kernel_launch(void* const* d_in, const int* in_sizes, int n_in,
                              void* d_out, int out_size, void* d_ws, size_t ws_size,
                              hipStream_t stream) {
  const int*   method_code    = (const int*)d_in[0];
  const int*   method_summary = (const int*)d_in[1];
  const float* enc_emb = (const float*)d_in[3];
  const float* enc_Wih = (const float*)d_in[4];
  const float* enc_Whh = (const float*)d_in[5];
  const float* enc_bih = (const float*)d_in[6];
  const float* enc_bhh = (const float*)d_in[7];
  const float* dec_emb = (const float*)d_in[8];
  const float* dec_Wih = (const float*)d_in[9];
  const float* dec_Whh = (const float*)d_in[10];
  const float* dec_bih = (const float*)d_in[11];
  const float* dec_bhh = (const float*)d_in[12];
  const float* W1 = (const float*)d_in[13];
  const float* b1 = (const float*)d_in[14];
  const float* W2 = (const float*)d_in[15];
  const float* b2 = (const float*)d_in[16];

  float* ws      = (float*)d_ws;
  float* enc_gx  = ws + OFF_ENC_GX;
  float* dec_gx  = ws + OFF_DEC_GX;
  float* enc_out = ws + OFF_ENC_OUT;
  float* hbuf    = ws + OFF_HBUF;
  float* Cmat    = ws + OFF_CMAT;
  float* OUT1    = ws + OFF_OUT1;

  // reset h exchange buffers (tags=0 == h_0 valid, payload zeros) every call
  hipMemsetAsync(hbuf, 0, SZ_HBUF * sizeof(float), stream);

  dim3 blk(WGS);
  // gx precompute (gather-GEMMs)
  gemm_bt<0><<<dim3(G3_ / 64, (S_ * B_) / 64), blk, 0, stream>>>(
      enc_emb, method_code, enc_Wih, enc_bih, enc_gx, S_ * B_, G3_, DE_);
  gemm_bt<1><<<dim3(G3_ / 64, (TD_ * B_ + 63) / 64), blk, 0, stream>>>(
      dec_emb, method_summary, dec_Wih, dec_bih, dec_gx, TD_ * B_, G3_, DE_);

  // persistent GRU chains: 512 WGs, barrier-free tagged-line exchange
  recurrence_kernel<<<NWGR, blk, 0, stream>>>(enc_gx, dec_gx,
                                              enc_Whh, enc_bhh, dec_Whh, dec_bhh,
                                              enc_out, hbuf, Cmat);

  // attention for all (td, b) in parallel
  attention_kernel<<<TD_ * B_, blk, 0, stream>>>(enc_out, Cmat);

  // output projection
  gemm_bt<2><<<dim3(H_ / 64, (TD_ * B_ + 63) / 64), blk, 0, stream>>>(
      Cmat, nullptr, W1, b1, OUT1, TD_ * B_, H_, 2 * H_);
  gemm128_out<<<dim3((VS_ + 127) / 128, (TD_ * B_ + 127) / 128), blk, 0, stream>>>(
      OUT1, W2, b2, (float*)d_out);
}

// Round 7
// 1792.736 us; speedup vs baseline: 8.5642x; 1.1613x over previous
//
#include <hip/hip_runtime.h>
#include <cmath>

#define WGS  256
#define NWGR 256         // recurrence workgroups (1 per CU)
#define DOMS 4           // independent batch domains (8 batches each)
#define JGN  64          // j-groups per domain (8 j each)
#define HBDW 5120        // dwords per parity buffer per domain (64 blocks x 80)

typedef float    f32x4 __attribute__((ext_vector_type(4)));
typedef unsigned u32x4 __attribute__((ext_vector_type(4)));

// ---------------- sizes ----------------
#define B_   32
#define S_   200
#define L_   50
#define H_   512
#define DE_  256
#define VS_  30000
#define TD_  49          // L-1 decoder steps
#define G3_  1536        // 3*H

// ws layout (float offsets)
#define OFF_ENC_GX  ((size_t)0)                         // [200][32][1536]
#define SZ_ENC_GX   ((size_t)S_*B_*G3_)
#define OFF_DEC_GX  (OFF_ENC_GX + SZ_ENC_GX)            // [49][32][1536]
#define SZ_DEC_GX   ((size_t)TD_*B_*G3_)
#define OFF_ENC_OUT (OFF_DEC_GX + SZ_DEC_GX)            // [32][200][512]
#define SZ_ENC_OUT  ((size_t)B_*S_*H_)
#define OFF_HBUF    (OFF_ENC_OUT + SZ_ENC_OUT)          // [dom4][buf2][5120] tagged
#define SZ_HBUF     ((size_t)DOMS*2*HBDW)               // 40960 floats
#define OFF_CMAT    (OFF_HBUF + SZ_HBUF)                // [49][32][1024]
#define SZ_CMAT     ((size_t)TD_*B_*2*H_)
#define OFF_OUT1    (OFF_CMAT + SZ_CMAT)                // [1568][512]
#define SZ_OUT1     ((size_t)TD_*B_*H_)

// LDS geometry: k-blocks of 64 floats @ stride 68 (<=2-way conflicts)
#define RSTR 548
#define KBLK 68

__device__ __forceinline__ u32x4 load_u4_cc(const unsigned* p) {
  u32x4 v;
  asm volatile("global_load_dwordx4 %0, %1, off sc0 sc1" : "=v"(v) : "v"(p) : "memory");
  return v;
}

__device__ __forceinline__ float dot4(f32x4 a, f32x4 b) {
  return a.x * b.x + a.y * b.y + a.z * b.z + a.w * b.w;
}

// ---------------- persistent GRU-chain kernel, barrier-free ----------------
// 256 WGs: dom = w>>6 (8 batches), jg = w&63 (8 j-values). Weights in VGPRs.
// Thread: jl = t&7 (j), kh = t>>3 (k-chunk of 16). Tail t<64: jl=t&7, bt=t>>3.
// Exchange block (per jg): 80 dwords = 5 cachelines; tag at pos%16==0, payload
// p = pos-1-pos/16 (p<64), p=(b<<3)+jl. Published by exactly 2 wave-store
// instructions (lanes 0-63 -> lines 0-3, lanes 0-15 -> line 4): each 64B line
// is written whole by one instruction -> tag+payload land atomically at L3.
__global__ __launch_bounds__(WGS)
void recurrence_kernel(const float* __restrict__ enc_gx,
                       const float* __restrict__ dec_gx,
                       const float* __restrict__ eWhh, const float* __restrict__ eBhh,
                       const float* __restrict__ dWhh, const float* __restrict__ dBhh,
                       float* __restrict__ enc_out,
                       float* __restrict__ hbuf,
                       float* __restrict__ Cmat)
{
  __shared__ float hlds[8 * RSTR];    // 17536 B: 8 batches x 512 k
  __shared__ float red[768];          //  3072 B: [wave4][jl8][g3][b8]

  const int t   = threadIdx.x;
  const int w   = blockIdx.x;
  const int dom = w >> 6;
  const int jg  = w & (JGN - 1);
  const int jl  = t & 7;
  const int kh  = t >> 3;             // 0..31 (compute role)
  const int bt_ = t >> 3;             // 0..7  (tail role, t<64)
  const int j   = (jg << 3) + jl;
  const int b_g = (dom << 3) + bt_;

  float* hdom = hbuf + (size_t)dom * (2 * HBDW);

  // staging constants: 5 dwordx4 loads; rr = dword offset within 80-dw block
  int rr[5], kb[5];
  #pragma unroll
  for (int i = 0; i < 5; ++i) {
    int g = i * 1024 + (t << 2);
    int blk = g / 80;
    rr[i] = g - blk * 80;
    kb[i] = blk << 3;                 // k base of the block
  }

  // weights in VGPRs: wreg[gate][k-subchunk], k = kh*16 + c*4 + lane-of-4
  f32x4 wreg[3][4];
  auto load_w = [&](const float* __restrict__ W) {
    #pragma unroll
    for (int g = 0; g < 3; ++g)
      #pragma unroll
      for (int c = 0; c < 4; ++c)
        wreg[g][c] = *(const f32x4*)(W + (size_t)(g * H_ + j) * H_ + (kh << 4) + (c << 2));
  };
  load_w(eWhh);

  float bias_r = 0.f, bias_z = 0.f, bias_n = 0.f;
  if (t < 64) { bias_r = eBhh[j]; bias_z = eBhh[H_ + j]; bias_n = eBhh[2 * H_ + j]; }

  for (int s = 0; s < S_ + TD_; ++s) {
    const bool enc = (s < S_);
    __syncthreads();    // hlds/red from prev step fully consumed
    if (s == S_) {      // switch to decoder weights
      load_w(dWhh);
      if (t < 64) { bias_r = dBhh[j]; bias_z = dBhh[H_ + j]; bias_n = dBhh[2 * H_ + j]; }
    }

    // gx for the tail (normal cached loads, issued early)
    float gxr = 0.f, gxz = 0.f, gxn = 0.f;
    if (t < 64) {
      const float* gx = enc ? (enc_gx + ((size_t)s * B_ + b_g) * G3_)
                            : (dec_gx + ((size_t)(s - S_) * B_ + b_g) * G3_);
      gxr = gx[j]; gxz = gx[H_ + j]; gxn = gx[2 * H_ + j];
    }

    // ---- stage h_s: poll tagged lines until fresh, scatter to LDS ----
    {
      const unsigned* hb = (const unsigned*)(hdom + (size_t)(s & 1) * HBDW);
      const unsigned tagreq = (unsigned)s;
      u32x4 v0, v1, v2, v3, v4;
      while (true) {
        v0 = load_u4_cc(hb + 0 * 1024 + (t << 2));
        v1 = load_u4_cc(hb + 1 * 1024 + (t << 2));
        v2 = load_u4_cc(hb + 2 * 1024 + (t << 2));
        v3 = load_u4_cc(hb + 3 * 1024 + (t << 2));
        v4 = load_u4_cc(hb + 4 * 1024 + (t << 2));
        asm volatile("s_waitcnt vmcnt(0)" ::: "memory");
        bool ok = true;
        if ((rr[0] & 15) == 0) ok &= ((unsigned)v0.x >= tagreq);
        if ((rr[1] & 15) == 0) ok &= ((unsigned)v1.x >= tagreq);
        if ((rr[2] & 15) == 0) ok &= ((unsigned)v2.x >= tagreq);
        if ((rr[3] & 15) == 0) ok &= ((unsigned)v3.x >= tagreq);
        if ((rr[4] & 15) == 0) ok &= ((unsigned)v4.x >= tagreq);
        if (__all(ok)) break;
        __builtin_amdgcn_s_sleep(1);
      }
      #define SCAT(vv, ii) { \
        _Pragma("unroll") \
        for (int d = 0; d < 4; ++d) { \
          int pos = rr[ii] + d; \
          if ((pos & 15) != 0) { \
            int p = pos - 1 - (pos >> 4); \
            if (p < 64) { \
              int bb = p >> 3, k = kb[ii] + (p & 7); \
              hlds[bb * RSTR + ((k >> 6) * KBLK) + (k & 63)] = __uint_as_float(vv[d]); \
            } } } }
      SCAT(v0, 0) SCAT(v1, 1) SCAT(v2, 2) SCAT(v3, 3) SCAT(v4, 4)
      #undef SCAT
    }
    __syncthreads();

    // ---- compute: 8 j x 3 gates, 16-k slice per thread, all 8 batches ----
    float acc[3][8];
    #pragma unroll
    for (int g = 0; g < 3; ++g)
      #pragma unroll
      for (int b = 0; b < 8; ++b) acc[g][b] = 0.f;

    const int hoff = (kh >> 2) * KBLK + ((kh & 3) << 4);
    #pragma unroll
    for (int b = 0; b < 8; ++b) {
      const float* hp = &hlds[b * RSTR + hoff];
      f32x4 h0 = *(const f32x4*)(hp);
      f32x4 h1 = *(const f32x4*)(hp + 4);
      f32x4 h2 = *(const f32x4*)(hp + 8);
      f32x4 h3 = *(const f32x4*)(hp + 12);
      #pragma unroll
      for (int g = 0; g < 3; ++g)
        acc[g][b] += dot4(wreg[g][0], h0) + dot4(wreg[g][1], h1)
                   + dot4(wreg[g][2], h2) + dot4(wreg[g][3], h3);
    }

    // fold kh within wave (kh bits 0..2 = t bits 3..5)
    #pragma unroll
    for (int g = 0; g < 3; ++g)
      #pragma unroll
      for (int b = 0; b < 8; ++b) {
        float v = acc[g][b];
        v += __shfl_xor(v, 8);
        v += __shfl_xor(v, 16);
        v += __shfl_xor(v, 32);
        acc[g][b] = v;
      }
    if ((t & 56) == 0) {                      // one lane per (wave, jl)
      const int base = ((t >> 6) * 8 + jl) * 24;
      #pragma unroll
      for (int g = 0; g < 3; ++g)
        #pragma unroll
        for (int b = 0; b < 8; ++b)
          red[base + g * 8 + b] = acc[g][b];
    }
    __syncthreads();

    // ---- tail (wave 0): combine 4 wave-partials, gate math, publish ----
    if (t < 64) {
      float ar = 0.f, az = 0.f, an = 0.f;
      #pragma unroll
      for (int ww = 0; ww < 4; ++ww) {
        const int base = (ww * 8 + jl) * 24;
        ar += red[base + bt_];
        az += red[base + 8 + bt_];
        an += red[base + 16 + bt_];
      }
      float rg = 1.f / (1.f + expf(-(gxr + ar + bias_r)));
      float zg = 1.f / (1.f + expf(-(gxz + az + bias_z)));
      float ng = tanhf(gxn + rg * (an + bias_n));
      float hprev = hlds[bt_ * RSTR + ((j >> 6) * KBLK) + (j & 63)];
      float hn = (1.f - zg) * ng + zg * hprev;
      if (enc) enc_out[((size_t)b_g * S_ + s) * H_ + j] = hn;
      else     Cmat[((size_t)(s - S_) * B_ + b_g) * (2 * H_) + H_ + j] = hn;

      // publish h_{s+1}: payload index p == tail thread index
      unsigned* pb = (unsigned*)(hdom + (size_t)((s + 1) & 1) * HBDW) + jg * 80;
      const unsigned tagv = (unsigned)(s + 1);
      // store A: lines 0-3 (dwords 0..63)
      float vA = __shfl(hn, (t - 1 - (t >> 4)) & 63);
      unsigned valA = ((t & 15) == 0) ? tagv : __float_as_uint(vA);
      __hip_atomic_store(pb + t, valA, __ATOMIC_RELAXED, __HIP_MEMORY_SCOPE_AGENT);
      // store B: line 4 (dwords 64..79; payloads p=60..63 at pos 65..68)
      float vB = __shfl(hn, (59 + t) & 63);
      if (t < 16) {
        unsigned valB = (t == 0) ? tagv : __float_as_uint(vB);
        __hip_atomic_store(pb + 64 + t, valB, __ATOMIC_RELAXED, __HIP_MEMORY_SCOPE_AGENT);
      }
    }
  }
}

// ---------------- attention kernel: one WG per (td, b) ----------------
__global__ __launch_bounds__(WGS)
void attention_kernel(const float* __restrict__ enc_out,
                      float* __restrict__ Cmat)
{
  const int task = blockIdx.x;          // td*32 + b
  const int td = task >> 5, b = task & 31;
  const int t = threadIdx.x;
  const float* h = Cmat + ((size_t)td * B_ + b) * (2 * H_) + H_;

  __shared__ float red[WGS];
  __shared__ float p[WGS];              // 200 used

  float sv = -1e30f;
  if (t < S_) {
    const float* eo = enc_out + ((size_t)b * S_ + t) * H_;
    float acc = 0.f;
    #pragma unroll 4
    for (int k = 0; k < H_; k += 4) {
      float4 e = *(const float4*)(eo + k);
      float4 hv = *(const float4*)(h + k);
      acc += e.x * hv.x + e.y * hv.y + e.z * hv.z + e.w * hv.w;
    }
    sv = acc;
  }
  red[t] = sv; __syncthreads();
  for (int o = 128; o; o >>= 1) { if (t < o) red[t] = fmaxf(red[t], red[t + o]); __syncthreads(); }
  float mx = red[0]; __syncthreads();
  float ev = (t < S_) ? expf(sv - mx) : 0.f;
  red[t] = ev; __syncthreads();
  for (int o = 128; o; o >>= 1) { if (t < o) red[t] += red[t + o]; __syncthreads(); }
  float inv = 1.f / red[0];
  p[t] = ev * inv;
  __syncthreads();

  const float* eo = enc_out + (size_t)b * S_ * H_ + (t << 1);
  float ax = 0.f, ay = 0.f;
  for (int i = 0; i < S_; ++i) {
    float pi = p[i];
    float2 v = *(const float2*)(eo + (size_t)i * H_);
    ax += pi * v.x; ay += pi * v.y;
  }
  float* cd = Cmat + ((size_t)td * B_ + b) * (2 * H_) + (t << 1);
  cd[0] = ax; cd[1] = ay;
}

// ---------------- tiled fp32 GEMM 64x64 (modes 0/1/2) ----------------
template<int MODE>
__launch_bounds__(WGS)
__global__ void gemm_bt(const float* __restrict__ A,
                        const int* __restrict__ idx,
                        const float* __restrict__ Bw,
                        const float* __restrict__ bias,
                        float* __restrict__ Cdst,
                        int M, int N, int K)
{
  const int BM = 64, BN = 64, BK = 16;
  __shared__ float As[BK][BM];
  __shared__ float Bs[BK][BN];
  __shared__ int toks[BM];
  const int m0 = blockIdx.y * BM, n0 = blockIdx.x * BN;
  const int t = threadIdx.x;
  const int tx = t & 15, ty = t >> 4;
  float acc[4][4] = {{0.f}};

  if (MODE <= 1) {
    if (t < BM) {
      int m = m0 + t;
      int tok = 0;
      if (m < M) {
        int bidx = m & 31, srow = m >> 5;
        tok = (MODE == 0) ? idx[bidx * S_ + srow] : idx[bidx * L_ + srow];
      }
      toks[t] = tok;
    }
    __syncthreads();
  }

  const int row = t >> 2, kk = (t & 3) * 4;
  for (int k0 = 0; k0 < K; k0 += BK) {
    {
      int m = m0 + row;
      float4 v = {0.f, 0.f, 0.f, 0.f};
      if (m < M) {
        const float* src = (MODE <= 1) ? (A + (size_t)toks[row] * K + k0 + kk)
                                       : (A + (size_t)m * K + k0 + kk);
        v = *(const float4*)src;
      }
      As[kk][row] = v.x; As[kk + 1][row] = v.y; As[kk + 2][row] = v.z; As[kk + 3][row] = v.w;
      int n = n0 + row;
      float4 wv = {0.f, 0.f, 0.f, 0.f};
      if (n < N) wv = *(const float4*)(Bw + (size_t)n * K + k0 + kk);
      Bs[kk][row] = wv.x; Bs[kk + 1][row] = wv.y; Bs[kk + 2][row] = wv.z; Bs[kk + 3][row] = wv.w;
    }
    __syncthreads();
    #pragma unroll
    for (int k = 0; k < BK; ++k) {
      float a[4], bq[4];
      *(float4*)a  = *(const float4*)&As[k][ty * 4];
      *(float4*)bq = *(const float4*)&Bs[k][tx * 4];
      #pragma unroll
      for (int i = 0; i < 4; ++i)
        #pragma unroll
        for (int jj = 0; jj < 4; ++jj)
          acc[i][jj] += a[i] * bq[jj];
    }
    __syncthreads();
  }

  #pragma unroll
  for (int i = 0; i < 4; ++i) {
    int m = m0 + ty * 4 + i;
    if (m >= M) continue;
    #pragma unroll
    for (int jj = 0; jj < 4; ++jj) {
      int n = n0 + tx * 4 + jj;
      if (n >= N) continue;
      float v = acc[i][jj] + bias[n];
      if (MODE == 2) v = fmaxf(v, 0.f);
      Cdst[(size_t)m * N + n] = v;
    }
  }
}

// ---------------- 128x128 fp32 GEMM for the vocab projection ----------------
__global__ __launch_bounds__(WGS)
void gemm128_out(const float* __restrict__ A,   // [M][512]
                 const float* __restrict__ Bw,  // [N][512]
                 const float* __restrict__ bias,
                 float* __restrict__ out)
{
  const int APAD = 132;
  __shared__ float As[16 * APAD];
  __shared__ float Bs[16 * APAD];
  const int n0 = blockIdx.x * 128, m0 = blockIdx.y * 128;
  const int t = threadIdx.x;
  const int tx = t & 15, ty = t >> 4;
  const int M = TD_ * B_, N = VS_, K = H_;

  float acc[8][8];
  #pragma unroll
  for (int i = 0; i < 8; ++i)
    #pragma unroll
    for (int jj = 0; jj < 8; ++jj) acc[i][jj] = 0.f;

  const int srow = t >> 2, skk = (t & 3) * 4;
  for (int k0 = 0; k0 < K; k0 += 16) {
    #pragma unroll
    for (int u = 0; u < 2; ++u) {
      int row = srow + u * 64;
      int m = m0 + row;
      f32x4 av = {0.f, 0.f, 0.f, 0.f};
      if (m < M) av = *(const f32x4*)(A + (size_t)m * K + k0 + skk);
      As[(skk + 0) * APAD + row] = av.x;
      As[(skk + 1) * APAD + row] = av.y;
      As[(skk + 2) * APAD + row] = av.z;
      As[(skk + 3) * APAD + row] = av.w;
      int n = n0 + row;
      f32x4 bv = {0.f, 0.f, 0.f, 0.f};
      if (n < N) bv = *(const f32x4*)(Bw + (size_t)n * K + k0 + skk);
      Bs[(skk + 0) * APAD + row] = bv.x;
      Bs[(skk + 1) * APAD + row] = bv.y;
      Bs[(skk + 2) * APAD + row] = bv.z;
      Bs[(skk + 3) * APAD + row] = bv.w;
    }
    __syncthreads();
    #pragma unroll
    for (int k = 0; k < 16; ++k) {
      f32x4 a0 = *(const f32x4*)&As[k * APAD + ty * 8];
      f32x4 a1 = *(const f32x4*)&As[k * APAD + ty * 8 + 4];
      f32x4 b0 = *(const f32x4*)&Bs[k * APAD + tx * 4];
      f32x4 b1 = *(const f32x4*)&Bs[k * APAD + 64 + tx * 4];
      float a[8] = {a0.x, a0.y, a0.z, a0.w, a1.x, a1.y, a1.z, a1.w};
      float bb[8] = {b0.x, b0.y, b0.z, b0.w, b1.x, b1.y, b1.z, b1.w};
      #pragma unroll
      for (int i = 0; i < 8; ++i)
        #pragma unroll
        for (int jj = 0; jj < 8; ++jj)
          acc[i][jj] += a[i] * bb[jj];
    }
    __syncthreads();
  }

  const bool edge = (n0 + 128 > N);
  f32x4 bias0 = {0,0,0,0}, bias1 = {0,0,0,0};
  if (!edge) {
    bias0 = *(const f32x4*)(bias + n0 + tx * 4);
    bias1 = *(const f32x4*)(bias + n0 + 64 + tx * 4);
  }
  #pragma unroll
  for (int i = 0; i < 8; ++i) {
    int m = m0 + ty * 8 + i;
    if (m >= M) continue;
    int bidx = m & 31, td = m >> 5;
    float* orow = out + ((size_t)bidx * TD_ + td) * (size_t)VS_;
    if (!edge) {
      f32x4 v0 = { acc[i][0] + bias0.x, acc[i][1] + bias0.y,
                   acc[i][2] + bias0.z, acc[i][3] + bias0.w };
      f32x4 v1 = { acc[i][4] + bias1.x, acc[i][5] + bias1.y,
                   acc[i][6] + bias1.z, acc[i][7] + bias1.w };
      *(f32x4*)(orow + n0 + tx * 4) = v0;
      *(f32x4*)(orow + n0 + 64 + tx * 4) = v1;
    } else {
      #pragma unroll
      for (int jj = 0; jj < 8; ++jj) {
        int n = n0 + (jj >> 2) * 64 + tx * 4 + (jj & 3);
        if (n < N) orow[n] = acc[i][jj] + bias[n];
      }
    }
  }
}

// ---------------- launch ----------------
extern "C" void kernel_launch(void* const* d_in, const int* in_sizes, int n_in,
                              void* d_out, int out_size, void* d_ws, size_t ws_size,
                              hipStream_t stream) {
  const int*   method_code    = (const int*)d_in[0];
  const int*   method_summary = (const int*)d_in[1];
  const float* enc_emb = (const float*)d_in[3];
  const float* enc_Wih = (const float*)d_in[4];
  const float* enc_Whh = (const float*)d_in[5];
  const float* enc_bih = (const float*)d_in[6];
  const float* enc_bhh = (const float*)d_in[7];
  const float* dec_emb = (const float*)d_in[8];
  const float* dec_Wih = (const float*)d_in[9];
  const float* dec_Whh = (const float*)d_in[10];
  const float* dec_bih = (const float*)d_in[11];
  const float* dec_bhh = (const float*)d_in[12];
  const float* W1 = (const float*)d_in[13];
  const float* b1 = (const float*)d_in[14];
  const float* W2 = (const float*)d_in[15];
  const float* b2 = (const float*)d_in[16];

  float* ws      = (float*)d_ws;
  float* enc_gx  = ws + OFF_ENC_GX;
  float* dec_gx  = ws + OFF_DEC_GX;
  float* enc_out = ws + OFF_ENC_OUT;
  float* hbuf    = ws + OFF_HBUF;
  float* Cmat    = ws + OFF_CMAT;
  float* OUT1    = ws + OFF_OUT1;

  // reset h exchange buffers (tags=0 == h_0 valid, payload zeros) every call
  hipMemsetAsync(hbuf, 0, SZ_HBUF * sizeof(float), stream);

  dim3 blk(WGS);
  // gx precompute (gather-GEMMs)
  gemm_bt<0><<<dim3(G3_ / 64, (S_ * B_) / 64), blk, 0, stream>>>(
      enc_emb, method_code, enc_Wih, enc_bih, enc_gx, S_ * B_, G3_, DE_);
  gemm_bt<1><<<dim3(G3_ / 64, (TD_ * B_ + 63) / 64), blk, 0, stream>>>(
      dec_emb, method_summary, dec_Wih, dec_bih, dec_gx, TD_ * B_, G3_, DE_);

  // persistent GRU chains: 256 WGs, barrier-free tagged-line exchange
  recurrence_kernel<<<NWGR, blk, 0, stream>>>(enc_gx, dec_gx,
                                              enc_Whh, enc_bhh, dec_Whh, dec_bhh,
                                              enc_out, hbuf, Cmat);

  // attention for all (td, b) in parallel
  attention_kernel<<<TD_ * B_, blk, 0, stream>>>(enc_out, Cmat);

  // output projection
  gemm_bt<2><<<dim3(H_ / 64, (TD_ * B_ + 63) / 64), blk, 0, stream>>>(
      Cmat, nullptr, W1, b1, OUT1, TD_ * B_, H_, 2 * H_);
  gemm128_out<<<dim3((VS_ + 127) / 128, (TD_ * B_ + 127) / 128), blk, 0, stream>>>(
      OUT1, W2, b2, (float*)d_out);
}